// Round 1
// baseline (909.358 us; speedup 1.0000x reference)
//
#include <hip/hip_runtime.h>
#include <math.h>

#define NC 80

__device__ __forceinline__ float relu6f(float x){ return fminf(fmaxf(x, 0.f), 6.f); }
__device__ __forceinline__ float sigmoidf(float x){ return 1.f/(1.f+expf(-x)); }

// ---------------------------------------------------------------------------
// Pointwise 96->48 conv + BN + ReLU6. Writes into channels [0,48) of a
// [bc,96,HW] buffer (the "primary" half of the ghost concat).
// 1 thread = 1 pixel, 48 accumulators; weights in LDS transposed [c][o],
// read as float4 broadcast (same addr across lanes -> no bank conflict).
// ---------------------------------------------------------------------------
__global__ __launch_bounds__(256) void pw_kernel(
    const float* __restrict__ x, float* __restrict__ out,
    const float* __restrict__ w,      // [48,96]
    const float* __restrict__ s1, const float* __restrict__ b1, // [48]
    int HW)
{
    __shared__ __align__(16) float wl[96*48];   // [c][o]
    for (int idx = threadIdx.x; idx < 96*48; idx += 256){
        int c = idx/48, o = idx - c*48;
        wl[idx] = w[o*96 + c];
    }
    __syncthreads();
    int p = blockIdx.x*256 + threadIdx.x;
    if (p >= HW) return;
    const float* xb = x + (size_t)blockIdx.y*96*HW + p;
    float acc[48];
    #pragma unroll
    for (int o=0;o<48;o++) acc[o] = 0.f;
    for (int c=0;c<96;c++){
        float xv = xb[c*HW];
        const float4* row = (const float4*)(&wl[c*48]);
        #pragma unroll
        for (int q=0;q<12;q++){
            float4 wv = row[q];
            acc[q*4+0] = fmaf(xv, wv.x, acc[q*4+0]);
            acc[q*4+1] = fmaf(xv, wv.y, acc[q*4+1]);
            acc[q*4+2] = fmaf(xv, wv.z, acc[q*4+2]);
            acc[q*4+3] = fmaf(xv, wv.w, acc[q*4+3]);
        }
    }
    float* ob = out + (size_t)blockIdx.y*96*HW + p;
    #pragma unroll
    for (int o=0;o<48;o++)
        ob[(size_t)o*HW] = relu6f(fmaf(acc[o], s1[o], b1[o]));
}

// ---------------------------------------------------------------------------
// Depthwise 3x3 (SAME, cross-correlation) + BN + ReLU6 on channels [0,48),
// writing into channels [48,96) of the same buffer (= the concat).
// grid: (ceil(HW/256), 48, bc)
// ---------------------------------------------------------------------------
__global__ __launch_bounds__(256) void dw_kernel(
    float* __restrict__ buf,
    const float* __restrict__ w,      // [48,3,3]
    const float* __restrict__ s2, const float* __restrict__ b2, // [48]
    int H, int W)
{
    int HW = H*W;
    int p = blockIdx.x*256 + threadIdx.x;
    if (p >= HW) return;
    int o = blockIdx.y;
    int b = blockIdx.z;
    int h = p / W, x0 = p - h*W;
    const float* yb = buf + ((size_t)b*96 + o)*HW;
    float acc = 0.f;
    #pragma unroll
    for (int ky=0;ky<3;ky++){
        int hy = h + ky - 1;
        if ((unsigned)hy >= (unsigned)H) continue;
        #pragma unroll
        for (int kx=0;kx<3;kx++){
            int wx = x0 + kx - 1;
            if ((unsigned)wx >= (unsigned)W) continue;
            acc = fmaf(yb[hy*W + wx], w[o*9 + ky*3 + kx], acc);
        }
    }
    buf[((size_t)b*96 + 48 + o)*HW + p] = relu6f(fmaf(acc, s2[o], b2[o]));
}

// ---------------------------------------------------------------------------
// Fused head: cls(80)+obj(1) GEMV from xc, reg(32) GEMV from xr, DFL decode,
// anchor box construction, sigmoid scores. 1 thread = 1 anchor.
// grid: (ceil(HW/256), bc)
// ---------------------------------------------------------------------------
__global__ __launch_bounds__(256) void head_kernel(
    const float* __restrict__ xc, const float* __restrict__ xr,
    const float* __restrict__ cls_w, const float* __restrict__ cls_b,
    const float* __restrict__ obj_w, const float* __restrict__ obj_b,
    const float* __restrict__ reg_w, const float* __restrict__ reg_b,
    float* __restrict__ boxes, float* __restrict__ scores,
    int HW, int W, float sc, int aoff, int b0)
{
    __shared__ __align__(16) float wc[96*NC];   // [c][n]
    __shared__ __align__(16) float wr[96*32];   // [c][n]
    __shared__ float wo[96];
    for (int idx = threadIdx.x; idx < 96*NC; idx += 256){
        int c = idx/NC, n = idx - c*NC;
        wc[idx] = cls_w[n*96 + c];
    }
    for (int idx = threadIdx.x; idx < 96*32; idx += 256){
        int c = idx/32, n = idx - c*32;
        wr[idx] = reg_w[n*96 + c];
    }
    if (threadIdx.x < 96) wo[threadIdx.x] = obj_w[threadIdx.x];
    __syncthreads();

    int a = blockIdx.x*256 + threadIdx.x;
    if (a >= HW) return;
    int b = blockIdx.y;

    // --- cls + obj GEMV ---
    const float* xcb = xc + (size_t)b*96*HW + a;
    float accc[NC];
    float acco = 0.f;
    #pragma unroll
    for (int n=0;n<NC;n++) accc[n] = 0.f;
    for (int c=0;c<96;c++){
        float v = xcb[c*HW];
        acco = fmaf(v, wo[c], acco);
        const float4* row = (const float4*)(&wc[c*NC]);
        #pragma unroll
        for (int q=0;q<NC/4;q++){
            float4 wv = row[q];
            accc[q*4+0] = fmaf(v, wv.x, accc[q*4+0]);
            accc[q*4+1] = fmaf(v, wv.y, accc[q*4+1]);
            accc[q*4+2] = fmaf(v, wv.z, accc[q*4+2]);
            accc[q*4+3] = fmaf(v, wv.w, accc[q*4+3]);
        }
    }
    int gb = b0 + b;
    size_t arow = (size_t)gb*8400 + aoff + a;
    float ol = acco + obj_b[0];
    float* srow = scores + arow*NC;
    for (int n=0;n<NC;n++)
        srow[n] = sigmoidf(accc[n] + cls_b[n] + ol);

    // --- reg GEMV ---
    float accr[32];
    #pragma unroll
    for (int n=0;n<32;n++) accr[n] = 0.f;
    const float* xrb = xr + (size_t)b*96*HW + a;
    for (int c=0;c<96;c++){
        float v = xrb[c*HW];
        const float4* row = (const float4*)(&wr[c*32]);
        #pragma unroll
        for (int q=0;q<8;q++){
            float4 wv = row[q];
            accr[q*4+0] = fmaf(v, wv.x, accr[q*4+0]);
            accr[q*4+1] = fmaf(v, wv.y, accr[q*4+1]);
            accr[q*4+2] = fmaf(v, wv.z, accr[q*4+2]);
            accr[q*4+3] = fmaf(v, wv.w, accr[q*4+3]);
        }
    }

    // --- DFL decode ---
    float ltrb[4];
    #pragma unroll
    for (int k=0;k<4;k++){
        float t[8]; float m = -1e30f;
        #pragma unroll
        for (int r=0;r<8;r++){ t[r] = accr[k*8+r] + reg_b[k*8+r]; m = fmaxf(m, t[r]); }
        float den = 0.f, num = 0.f;
        #pragma unroll
        for (int r=0;r<8;r++){ float e = expf(t[r]-m); den += e; num = fmaf(e, (float)r, num); }
        ltrb[k] = num/den * sc;
    }
    int ay_i = a / W;
    float ax = ((float)(a - ay_i*W) + 0.5f) * sc;
    float ay = ((float)ay_i + 0.5f) * sc;
    float* brow = boxes + arow*4;
    brow[0] = ax - ltrb[0];
    brow[1] = ay - ltrb[1];
    brow[2] = ax + ltrb[2];
    brow[3] = ay + ltrb[3];
}

// ---------------------------------------------------------------------------
extern "C" void kernel_launch(void* const* d_in, const int* in_sizes, int n_in,
                              void* d_out, int out_size, void* d_ws, size_t ws_size,
                              hipStream_t stream)
{
    const float* feat[3] = {(const float*)d_in[0], (const float*)d_in[1], (const float*)d_in[2]};
    const float* primary_w = (const float*)d_in[3];   // [2,2,48,96]
    const float* bn1_s     = (const float*)d_in[4];   // [2,2,48]
    const float* bn1_b     = (const float*)d_in[5];
    const float* cheap_w   = (const float*)d_in[6];   // [2,2,48,1,3,3]
    const float* bn2_s     = (const float*)d_in[7];
    const float* bn2_b     = (const float*)d_in[8];
    const float* cls_w     = (const float*)d_in[9];   // [3,80,96]
    const float* cls_b     = (const float*)d_in[10];  // [3,80]
    const float* obj_w     = (const float*)d_in[11];  // [3,1,96]
    const float* obj_b     = (const float*)d_in[12];  // [3,1]
    const float* reg_w     = (const float*)d_in[13];  // [3,32,96]
    const float* reg_b     = (const float*)d_in[14];  // [3,32]

    const int B = 16;
    const int Hs[3] = {80, 40, 20};
    const float strds[3] = {8.f, 16.f, 32.f};
    const int aoffs[3] = {0, 6400, 8000};

    float* boxes  = (float*)d_out;                      // [16,8400,4]
    float* scores = (float*)d_out + (size_t)16*8400*4;  // [16,8400,80]

    // 3 ping-pong buffers of [bc,96,80,80] fp32; chunk batch to fit ws_size.
    const size_t bufElemsPerB = (size_t)96*6400;
    int bc = 16;
    while (bc > 1 && 3*(size_t)bc*bufElemsPerB*4 > ws_size) bc >>= 1;
    float* bufA = (float*)d_ws;
    float* bufB = bufA + (size_t)bc*bufElemsPerB;
    float* bufC = bufB + (size_t)bc*bufElemsPerB;

    for (int lev=0; lev<3; lev++){
        int H = Hs[lev], W = H, HW = H*W;
        int gx = (HW + 255)/256;
        for (int b0=0; b0<B; b0+=bc){
            const float* f = feat[lev] + (size_t)b0*96*HW;
            // pass order: cls L0 (f->A), cls L1 (A->B), reg L0 (f->A), reg L1 (A->C)
            const float* ins[4]  = { f, bufA, f, bufA };
            float*       outs[4] = { bufA, bufB, bufA, bufC };
            const int    brs[4]  = { 0, 0, 1, 1 };
            for (int pi=0; pi<4; pi++){
                int li = pi & 1;
                int pl = brs[pi]*2 + li;
                pw_kernel<<<dim3(gx, bc), 256, 0, stream>>>(
                    ins[pi], outs[pi],
                    primary_w + (size_t)pl*48*96, bn1_s + pl*48, bn1_b + pl*48, HW);
                dw_kernel<<<dim3(gx, 48, bc), 256, 0, stream>>>(
                    outs[pi],
                    cheap_w + (size_t)pl*48*9, bn2_s + pl*48, bn2_b + pl*48, H, W);
            }
            head_kernel<<<dim3(gx, bc), 256, 0, stream>>>(
                bufB, bufC,
                cls_w + (size_t)lev*NC*96, cls_b + (size_t)lev*NC,
                obj_w + (size_t)lev*96,    obj_b + lev,
                reg_w + (size_t)lev*32*96, reg_b + (size_t)lev*32,
                boxes, scores, HW, W, strds[lev], aoffs[lev], b0);
        }
    }
}

// Round 2
// 579.776 us; speedup vs baseline: 1.5685x; 1.5685x over previous
//
#include <hip/hip_runtime.h>
#include <math.h>

#define NC 80

__device__ __forceinline__ float relu6f(float x){ return fminf(fmaxf(x, 0.f), 6.f); }
__device__ __forceinline__ float sigmoidf(float x){ return 1.f/(1.f+expf(-x)); }

// ---------------------------------------------------------------------------
// Pointwise 96->48 conv + BN + ReLU6 for BOTH branches (cls/reg) in one
// dispatch. grid = (ceil(HW/128), bc, 2); block = 256.
// Thread tile: 2 pixels x 12 channels. ct = tid>>6 picks channel slice
// (wave-uniform -> LDS reads are pure broadcast), tp = tid&63 picks pixels.
// ---------------------------------------------------------------------------
__global__ __launch_bounds__(256) void pw_kernel(
    const float* __restrict__ xc_in, const float* __restrict__ xr_in,
    float* __restrict__ out_c, float* __restrict__ out_r,
    const float* __restrict__ primary_w,   // [2,2,48,96]
    const float* __restrict__ bn1_s, const float* __restrict__ bn1_b, // [2,2,48]
    int li, int HW)
{
    __shared__ __align__(16) float wl[96*48];   // [c][o]
    __shared__ float s1l[48], b1l[48];
    int br = blockIdx.z;
    int pl = br*2 + li;
    const float* w = primary_w + (size_t)pl*48*96;
    for (int idx = threadIdx.x; idx < 96*48; idx += 256){
        int c = idx/48, o = idx - c*48;
        wl[idx] = w[o*96 + c];
    }
    if (threadIdx.x < 48){
        s1l[threadIdx.x] = bn1_s[pl*48 + threadIdx.x];
        b1l[threadIdx.x] = bn1_b[pl*48 + threadIdx.x];
    }
    __syncthreads();

    int ct = threadIdx.x >> 6;        // 0..3 -> channels [ct*12, ct*12+12)
    int tp = threadIdx.x & 63;
    int p0 = blockIdx.x*128 + tp*2;   // HW is even at every level
    if (p0 >= HW) return;

    size_t boff = (size_t)blockIdx.y*96*HW;
    const float* x = (br ? xr_in : xc_in) + boff + p0;
    float* out = (br ? out_r : out_c) + boff + p0;

    float a0[12], a1[12];
    #pragma unroll
    for (int o=0;o<12;o++){ a0[o]=0.f; a1[o]=0.f; }

    const float4* wv4 = (const float4*)wl;
    #pragma unroll 4
    for (int c=0;c<96;c++){
        float2 xv = *(const float2*)(x + (size_t)c*HW);
        float4 wq[3];
        wq[0] = wv4[c*12 + ct*3 + 0];
        wq[1] = wv4[c*12 + ct*3 + 1];
        wq[2] = wv4[c*12 + ct*3 + 2];
        const float* wf = (const float*)wq;
        #pragma unroll
        for (int o=0;o<12;o++){
            a0[o] = fmaf(xv.x, wf[o], a0[o]);
            a1[o] = fmaf(xv.y, wf[o], a1[o]);
        }
    }
    #pragma unroll
    for (int o=0;o<12;o++){
        int oc = ct*12 + o;
        float sv = s1l[oc], bv = b1l[oc];
        float2 r;
        r.x = relu6f(fmaf(a0[o], sv, bv));
        r.y = relu6f(fmaf(a1[o], sv, bv));
        *(float2*)(out + (size_t)oc*HW) = r;
    }
}

// ---------------------------------------------------------------------------
// Depthwise 3x3 + BN + ReLU6, both branches. Writes channels [48,96).
// grid = (ceil(HW/256), 96, bc)  (y = br*48 + o)
// ---------------------------------------------------------------------------
__global__ __launch_bounds__(256) void dw_kernel(
    float* __restrict__ bufc, float* __restrict__ bufr,
    const float* __restrict__ cheap_w,   // [2,2,48,3,3]
    const float* __restrict__ bn2_s, const float* __restrict__ bn2_b,
    int li, int H, int W)
{
    int HW = H*W;
    int p = blockIdx.x*256 + threadIdx.x;
    if (p >= HW) return;
    int y = blockIdx.y;
    int br = (y >= 48) ? 1 : 0;
    int o = y - br*48;
    int b = blockIdx.z;
    int pl = br*2 + li;
    float* buf = (br ? bufr : bufc) + (size_t)b*96*HW;
    const float* wp = cheap_w + (size_t)(pl*48 + o)*9;
    float s2 = bn2_s[pl*48 + o], b2v = bn2_b[pl*48 + o];
    int h = p / W, x0 = p - h*W;
    const float* yb = buf + (size_t)o*HW;
    float acc = 0.f;
    #pragma unroll
    for (int ky=0;ky<3;ky++){
        int hy = h + ky - 1;
        if ((unsigned)hy >= (unsigned)H) continue;
        #pragma unroll
        for (int kx=0;kx<3;kx++){
            int wx = x0 + kx - 1;
            if ((unsigned)wx >= (unsigned)W) continue;
            acc = fmaf(yb[hy*W + wx], wp[ky*3 + kx], acc);
        }
    }
    buf[(size_t)(48 + o)*HW + p] = relu6f(fmaf(acc, s2, b2v));
}

// ---------------------------------------------------------------------------
// Head cls+obj: scores = sigmoid(cls + obj). Thread tile: 2 anchors x 20 cls
// channels; obj recomputed per channel-slice (5% overhead, avoids exchange).
// grid = (ceil(HW/128), bc)
// ---------------------------------------------------------------------------
__global__ __launch_bounds__(256) void head_cls_kernel(
    const float* __restrict__ xc,
    const float* __restrict__ cls_w, const float* __restrict__ cls_b,
    const float* __restrict__ obj_w, const float* __restrict__ obj_b,
    float* __restrict__ scores,
    int HW, int aoff, int b0)
{
    __shared__ __align__(16) float wc[96*NC];   // [c][n]
    __shared__ float wo[96];
    __shared__ float cbl[NC];
    for (int idx = threadIdx.x; idx < 96*NC; idx += 256){
        int c = idx/NC, n = idx - c*NC;
        wc[idx] = cls_w[n*96 + c];
    }
    if (threadIdx.x < 96) wo[threadIdx.x] = obj_w[threadIdx.x];
    if (threadIdx.x < NC) cbl[threadIdx.x] = cls_b[threadIdx.x];
    __syncthreads();

    int ct = threadIdx.x >> 6;        // 0..3 -> cls channels [ct*20, ct*20+20)
    int tp = threadIdx.x & 63;
    int a0 = blockIdx.x*128 + tp*2;
    if (a0 >= HW) return;
    int b = blockIdx.y;
    const float* xb = xc + (size_t)b*96*HW + a0;

    float acc0[20], acc1[20], ob0 = 0.f, ob1 = 0.f;
    #pragma unroll
    for (int n=0;n<20;n++){ acc0[n]=0.f; acc1[n]=0.f; }

    const float4* wv4 = (const float4*)wc;
    #pragma unroll 2
    for (int c=0;c<96;c++){
        float2 xv = *(const float2*)(xb + (size_t)c*HW);
        float ov = wo[c];
        ob0 = fmaf(xv.x, ov, ob0);
        ob1 = fmaf(xv.y, ov, ob1);
        float4 wq[5];
        #pragma unroll
        for (int q=0;q<5;q++) wq[q] = wv4[c*20 + ct*5 + q];
        const float* wf = (const float*)wq;
        #pragma unroll
        for (int n=0;n<20;n++){
            acc0[n] = fmaf(xv.x, wf[n], acc0[n]);
            acc1[n] = fmaf(xv.y, wf[n], acc1[n]);
        }
    }
    float obv = obj_b[0];
    ob0 += obv; ob1 += obv;
    size_t arow = (size_t)(b0 + b)*8400 + aoff + a0;
    float* s0 = scores + arow*NC + ct*20;
    float* s1p = s0 + NC;
    #pragma unroll
    for (int n=0;n<20;n++){
        float cb = cbl[ct*20 + n];
        s0[n]  = sigmoidf(acc0[n] + cb + ob0);
        s1p[n] = sigmoidf(acc1[n] + cb + ob1);
    }
}

// ---------------------------------------------------------------------------
// Head reg + DFL + boxes. Thread tile: 1 anchor x 16 reg channels = one
// k-pair (ct=0 -> k{0,1} -> x1,y1; ct=1 -> k{2,3} -> x2,y2).
// grid = (ceil(HW/128), bc)
// ---------------------------------------------------------------------------
__global__ __launch_bounds__(256) void head_reg_kernel(
    const float* __restrict__ xr,
    const float* __restrict__ reg_w, const float* __restrict__ reg_b,
    float* __restrict__ boxes,
    int HW, int W, float sc, int aoff, int b0)
{
    __shared__ __align__(16) float wr[96*32];   // [c][n]
    __shared__ float rbl[32];
    for (int idx = threadIdx.x; idx < 96*32; idx += 256){
        int c = idx/32, n = idx & 31;
        wr[idx] = reg_w[n*96 + c];
    }
    if (threadIdx.x < 32) rbl[threadIdx.x] = reg_b[threadIdx.x];
    __syncthreads();

    int ct = threadIdx.x >> 7;        // 0/1 -> reg channels [ct*16, ct*16+16)
    int tp = threadIdx.x & 127;
    int a = blockIdx.x*128 + tp;
    if (a >= HW) return;
    int b = blockIdx.y;
    const float* xb = xr + (size_t)b*96*HW + a;

    float acc[16];
    #pragma unroll
    for (int n=0;n<16;n++) acc[n]=0.f;

    const float4* wv4 = (const float4*)wr;
    #pragma unroll 4
    for (int c=0;c<96;c++){
        float xv = xb[(size_t)c*HW];
        float4 wq[4];
        #pragma unroll
        for (int q=0;q<4;q++) wq[q] = wv4[c*8 + ct*4 + q];
        const float* wf = (const float*)wq;
        #pragma unroll
        for (int n=0;n<16;n++)
            acc[n] = fmaf(xv, wf[n], acc[n]);
    }

    float l2[2];
    #pragma unroll
    for (int kk=0;kk<2;kk++){
        float t[8]; float m = -1e30f;
        #pragma unroll
        for (int r=0;r<8;r++){ t[r] = acc[kk*8+r] + rbl[ct*16 + kk*8 + r]; m = fmaxf(m, t[r]); }
        float den = 0.f, num = 0.f;
        #pragma unroll
        for (int r=0;r<8;r++){ float e = expf(t[r]-m); den += e; num = fmaf(e, (float)r, num); }
        l2[kk] = num/den * sc;
    }
    int ay_i = a / W;
    float ax = ((float)(a - ay_i*W) + 0.5f) * sc;
    float ay = ((float)ay_i + 0.5f) * sc;
    size_t arow = (size_t)(b0 + b)*8400 + aoff + a;
    float2 r2;
    if (ct == 0){ r2.x = ax - l2[0]; r2.y = ay - l2[1]; }
    else        { r2.x = ax + l2[0]; r2.y = ay + l2[1]; }
    *(float2*)(boxes + arow*4 + ct*2) = r2;
}

// ---------------------------------------------------------------------------
extern "C" void kernel_launch(void* const* d_in, const int* in_sizes, int n_in,
                              void* d_out, int out_size, void* d_ws, size_t ws_size,
                              hipStream_t stream)
{
    const float* feat[3] = {(const float*)d_in[0], (const float*)d_in[1], (const float*)d_in[2]};
    const float* primary_w = (const float*)d_in[3];
    const float* bn1_s     = (const float*)d_in[4];
    const float* bn1_b     = (const float*)d_in[5];
    const float* cheap_w   = (const float*)d_in[6];
    const float* bn2_s     = (const float*)d_in[7];
    const float* bn2_b     = (const float*)d_in[8];
    const float* cls_w     = (const float*)d_in[9];
    const float* cls_b     = (const float*)d_in[10];
    const float* obj_w     = (const float*)d_in[11];
    const float* obj_b     = (const float*)d_in[12];
    const float* reg_w     = (const float*)d_in[13];
    const float* reg_b     = (const float*)d_in[14];

    const int B = 16;
    const int Hs[3] = {80, 40, 20};
    const float strds[3] = {8.f, 16.f, 32.f};
    const int aoffs[3] = {0, 6400, 8000};

    float* boxes  = (float*)d_out;
    float* scores = (float*)d_out + (size_t)16*8400*4;

    // 4 buffers of [bc,96,80,80] fp32; chunk batch to fit ws_size.
    const size_t perB = (size_t)96*6400;
    int bc = 16;
    while (bc > 1 && 4*(size_t)bc*perB*4 > ws_size) bc >>= 1;
    float* bufA = (float*)d_ws;
    float* bufB = bufA + (size_t)bc*perB;
    float* bufC = bufB + (size_t)bc*perB;
    float* bufD = bufC + (size_t)bc*perB;

    for (int lev=0; lev<3; lev++){
        int H = Hs[lev], W = H, HW = H*W;
        int gxPw = (HW + 127)/128;
        int gxDw = (HW + 255)/256;
        for (int b0=0; b0<B; b0+=bc){
            const float* f = feat[lev] + (size_t)b0*96*HW;
            // L0: f -> A (cls), f -> C (reg)
            pw_kernel<<<dim3(gxPw, bc, 2), 256, 0, stream>>>(
                f, f, bufA, bufC, primary_w, bn1_s, bn1_b, 0, HW);
            dw_kernel<<<dim3(gxDw, 96, bc), 256, 0, stream>>>(
                bufA, bufC, cheap_w, bn2_s, bn2_b, 0, H, W);
            // L1: A -> B (cls), C -> D (reg)
            pw_kernel<<<dim3(gxPw, bc, 2), 256, 0, stream>>>(
                bufA, bufC, bufB, bufD, primary_w, bn1_s, bn1_b, 1, HW);
            dw_kernel<<<dim3(gxDw, 96, bc), 256, 0, stream>>>(
                bufB, bufD, cheap_w, bn2_s, bn2_b, 1, H, W);
            // heads
            head_cls_kernel<<<dim3(gxPw, bc), 256, 0, stream>>>(
                bufB, cls_w + (size_t)lev*NC*96, cls_b + (size_t)lev*NC,
                obj_w + (size_t)lev*96, obj_b + lev,
                scores, HW, aoffs[lev], b0);
            head_reg_kernel<<<dim3(gxPw, bc), 256, 0, stream>>>(
                bufD, reg_w + (size_t)lev*32*96, reg_b + (size_t)lev*32,
                boxes, HW, W, strds[lev], aoffs[lev], b0);
        }
    }
}

// Round 3
// 238.580 us; speedup vs baseline: 3.8115x; 2.4301x over previous
//
#include <hip/hip_runtime.h>
#include <math.h>

#define NC 80

__device__ __forceinline__ float relu6f(float x){ return fminf(fmaxf(x, 0.f), 6.f); }
__device__ __forceinline__ float sigmoidf(float x){ return 1.f/(1.f+__expf(-x)); }
__device__ __forceinline__ float bf2f(unsigned int u){
    union { unsigned int i; float f; } v; v.i = u<<16; return v.f; }
__device__ __forceinline__ unsigned int f2bf(float f){
    union { float f; unsigned int i; } v; v.f = f;
    unsigned int r = v.i + 0x7fff + ((v.i>>16)&1);
    return r>>16; }

// ---------------------------------------------------------------------------
// Pointwise 96->48 + BN + ReLU6, both branches, ALL levels in one dispatch.
// grid = (34, bc, 2); block 256 = 4ct(12ch) x 64tp(4px).
// FIRST=1 reads fp32 feats; else bf16 buffer. Output bf16 channels [0,48).
// Depth-2 software prefetch on the x vector.
// ---------------------------------------------------------------------------
template<int FIRST>
__global__ __launch_bounds__(256) void pw_kernel(
    const float* __restrict__ f0, const float* __restrict__ f1, const float* __restrict__ f2,
    const unsigned short* __restrict__ inc, const unsigned short* __restrict__ inr,
    unsigned short* __restrict__ outc, unsigned short* __restrict__ outr,
    const float* __restrict__ primary_w,
    const float* __restrict__ bn1_s, const float* __restrict__ bn1_b,
    int li)
{
    __shared__ __align__(16) float wl[96*48];   // [c][o]
    __shared__ float s1l[48], b1l[48];
    int br = blockIdx.z;
    int pl = br*2 + li;
    const float* w = primary_w + (size_t)pl*48*96;
    for (int idx = threadIdx.x; idx < 96*48; idx += 256){
        int c = idx/48, o = idx - c*48;
        wl[idx] = w[o*96 + c];
    }
    if (threadIdx.x < 48){
        s1l[threadIdx.x] = bn1_s[pl*48 + threadIdx.x];
        b1l[threadIdx.x] = bn1_b[pl*48 + threadIdx.x];
    }
    __syncthreads();

    int bx = blockIdx.x;
    int lev, pb, HW, aoff;
    if (bx < 25){ lev=0; pb = bx<<8;      HW=6400; aoff=0;    }
    else if (bx < 32){ lev=1; pb = (bx-25)<<8; HW=1600; aoff=6400; }
    else { lev=2; pb = (bx-32)<<8; HW=400;  aoff=8000; }

    int ct = threadIdx.x >> 6;      // channel slice [ct*12, ct*12+12)
    int tp = threadIdx.x & 63;
    int p0 = pb + tp*4;
    if (p0 >= HW) return;
    int b = blockIdx.y;

    const float* fsrc = nullptr;
    const unsigned short* bsrc = nullptr;
    if (FIRST){
        const float* f = (lev==0)? f0 : (lev==1)? f1 : f2;
        fsrc = f + (size_t)b*96*HW + p0;
    } else {
        bsrc = (br ? inr : inc) + (size_t)b*96*8400 + aoff + p0;
    }
    unsigned short* dst = (br ? outr : outc) + (size_t)b*96*8400 + aoff + p0;

    float acc[12][4];
    #pragma unroll
    for (int o=0;o<12;o++)
        #pragma unroll
        for (int j=0;j<4;j++) acc[o][j]=0.f;

    const float4* wv4 = (const float4*)wl;
    int ct3 = ct*3;

    auto LDX = [&](int c)->float4{
        if (FIRST){
            return *(const float4*)(fsrc + (size_t)c*HW);
        } else {
            uint2 u = *(const uint2*)(bsrc + (size_t)c*8400);
            float4 r;
            r.x = bf2f(u.x & 0xffffu); r.y = bf2f(u.x >> 16);
            r.z = bf2f(u.y & 0xffffu); r.w = bf2f(u.y >> 16);
            return r;
        }
    };
    auto body = [&](int c, const float4& xv){
        #pragma unroll
        for (int q=0;q<3;q++){
            float4 wv = wv4[c*12 + ct3 + q];
            #pragma unroll
            for (int k=0;k<4;k++){
                float wk = (k==0)?wv.x:(k==1)?wv.y:(k==2)?wv.z:wv.w;
                int o = q*4 + k;
                acc[o][0] = fmaf(xv.x, wk, acc[o][0]);
                acc[o][1] = fmaf(xv.y, wk, acc[o][1]);
                acc[o][2] = fmaf(xv.z, wk, acc[o][2]);
                acc[o][3] = fmaf(xv.w, wk, acc[o][3]);
            }
        }
    };

    float4 xa = LDX(0), xb = LDX(1);
    #pragma unroll 4
    for (int c=0; c<94; c++){
        float4 xn = LDX(c+2);
        body(c, xa);
        xa = xb; xb = xn;
    }
    body(94, xa);
    body(95, xb);

    #pragma unroll
    for (int o=0;o<12;o++){
        int oc = ct*12 + o;
        float sv = s1l[oc], bv = b1l[oc];
        uint2 u;
        u.x = f2bf(relu6f(fmaf(acc[o][0], sv, bv))) |
             (f2bf(relu6f(fmaf(acc[o][1], sv, bv))) << 16);
        u.y = f2bf(relu6f(fmaf(acc[o][2], sv, bv))) |
             (f2bf(relu6f(fmaf(acc[o][3], sv, bv))) << 16);
        *(uint2*)(dst + (size_t)oc*8400) = u;
    }
}

// ---------------------------------------------------------------------------
// Depthwise 3x3 + BN + ReLU6, both branches, all levels.
// grid = (10, 96, bc); block 256, 4px/thread (row-aligned since W%4==0).
// Reads bf16 ch [0,48), writes bf16 ch [48,96).
// ---------------------------------------------------------------------------
__global__ __launch_bounds__(256) void dw_kernel(
    unsigned short* __restrict__ bufc, unsigned short* __restrict__ bufr,
    const float* __restrict__ cheap_w,
    const float* __restrict__ bn2_s, const float* __restrict__ bn2_b,
    int li)
{
    int bx = blockIdx.x;
    int lev, pb, HW, W, aoff;
    if (bx < 7){ lev=0; pb = bx<<10;      HW=6400; W=80; aoff=0;    }
    else if (bx < 9){ lev=1; pb = (bx-7)<<10; HW=1600; W=40; aoff=6400; }
    else { lev=2; pb = 0; HW=400; W=20; aoff=8000; }

    int p0 = pb + threadIdx.x*4;
    if (p0 >= HW) return;
    int y = blockIdx.y;
    int br = (y >= 48) ? 1 : 0;
    int o = br ? y-48 : y;
    int pl = br*2 + li;
    int b = blockIdx.z;

    unsigned short* base = (br ? bufr : bufc) + ((size_t)b*96 + o)*8400 + aoff;
    const float* wp = cheap_w + (size_t)(pl*48 + o)*9;
    float w[9];
    #pragma unroll
    for (int i=0;i<9;i++) w[i] = wp[i];
    float s2 = bn2_s[pl*48 + o], b2v = bn2_b[pl*48 + o];

    int h = (lev==0) ? (p0/80) : (lev==1) ? (p0/40) : (p0/20);
    int x0 = p0 - h*W;

    float acc0=0.f, acc1=0.f, acc2=0.f, acc3=0.f;
    #pragma unroll
    for (int dy=0; dy<3; dy++){
        int hy = h + dy - 1;
        if ((unsigned)hy >= (unsigned)W) continue;   // H == W (square)
        const unsigned short* rp = base + hy*W + x0;
        uint2 u = *(const uint2*)rp;
        float m0 = bf2f(u.x & 0xffffu), m1 = bf2f(u.x >> 16);
        float m2 = bf2f(u.y & 0xffffu), m3 = bf2f(u.y >> 16);
        float lf = (x0 > 0)      ? bf2f((unsigned int)rp[-1]) : 0.f;
        float rg = (x0 + 4 < W)  ? bf2f((unsigned int)rp[4])  : 0.f;
        float w0 = w[dy*3], w1 = w[dy*3+1], w2 = w[dy*3+2];
        acc0 = fmaf(lf,w0, fmaf(m0,w1, fmaf(m1,w2, acc0)));
        acc1 = fmaf(m0,w0, fmaf(m1,w1, fmaf(m2,w2, acc1)));
        acc2 = fmaf(m1,w0, fmaf(m2,w1, fmaf(m3,w2, acc2)));
        acc3 = fmaf(m2,w0, fmaf(m3,w1, fmaf(rg,w2, acc3)));
    }
    unsigned short* dst = (br ? bufr : bufc) + ((size_t)b*96 + 48 + o)*8400 + aoff + p0;
    uint2 u;
    u.x = f2bf(relu6f(fmaf(acc0, s2, b2v))) | (f2bf(relu6f(fmaf(acc1, s2, b2v))) << 16);
    u.y = f2bf(relu6f(fmaf(acc2, s2, b2v))) | (f2bf(relu6f(fmaf(acc3, s2, b2v))) << 16);
    *(uint2*)dst = u;
}

// ---------------------------------------------------------------------------
// Head cls+obj, all levels. grid = (67, bc); block 256 = 4ct(20ch) x 64tp(2px).
// ---------------------------------------------------------------------------
__global__ __launch_bounds__(256) void head_cls_kernel(
    const unsigned short* __restrict__ xc,
    const float* __restrict__ cls_w_all, const float* __restrict__ cls_b_all,
    const float* __restrict__ obj_w_all, const float* __restrict__ obj_b_all,
    float* __restrict__ scores, int b0)
{
    int bx = blockIdx.x;
    int lev, pb, HW, aoff;
    if (bx < 50){ lev=0; pb = bx<<7;      HW=6400; aoff=0;    }
    else if (bx < 63){ lev=1; pb = (bx-50)<<7; HW=1600; aoff=6400; }
    else { lev=2; pb = (bx-63)<<7; HW=400;  aoff=8000; }

    __shared__ __align__(16) float wc[96*NC];   // [c][n]
    __shared__ float wo[96], cbl[NC];
    const float* cls_w = cls_w_all + (size_t)lev*NC*96;
    for (int idx = threadIdx.x; idx < 96*NC; idx += 256){
        int c = idx/NC, n = idx - c*NC;
        wc[idx] = cls_w[n*96 + c];
    }
    if (threadIdx.x < 96) wo[threadIdx.x] = obj_w_all[lev*96 + threadIdx.x];
    if (threadIdx.x < NC) cbl[threadIdx.x] = cls_b_all[lev*NC + threadIdx.x];
    __syncthreads();

    int ct = threadIdx.x >> 6;
    int tp = threadIdx.x & 63;
    int p0 = pb + tp*2;
    if (p0 >= HW) return;
    int b = blockIdx.y;
    const unsigned short* xb = xc + (size_t)b*96*8400 + aoff + p0;

    float acc[20][2];
    #pragma unroll
    for (int n=0;n<20;n++){ acc[n][0]=0.f; acc[n][1]=0.f; }
    float ob0 = 0.f, ob1 = 0.f;
    const float4* wv4 = (const float4*)wc;
    int ct5 = ct*5;

    auto body = [&](int c, unsigned int u){
        float xx = bf2f(u & 0xffffu), xy = bf2f(u >> 16);
        float ov = wo[c];
        ob0 = fmaf(xx, ov, ob0);
        ob1 = fmaf(xy, ov, ob1);
        #pragma unroll
        for (int q=0;q<5;q++){
            float4 wv = wv4[c*20 + ct5 + q];
            #pragma unroll
            for (int k=0;k<4;k++){
                float wk = (k==0)?wv.x:(k==1)?wv.y:(k==2)?wv.z:wv.w;
                int n = q*4 + k;
                acc[n][0] = fmaf(xx, wk, acc[n][0]);
                acc[n][1] = fmaf(xy, wk, acc[n][1]);
            }
        }
    };

    unsigned int ua = *(const unsigned int*)(xb);
    unsigned int ub = *(const unsigned int*)(xb + 8400);
    #pragma unroll 4
    for (int c=0; c<94; c++){
        unsigned int un = *(const unsigned int*)(xb + (size_t)(c+2)*8400);
        body(c, ua);
        ua = ub; ub = un;
    }
    body(94, ua);
    body(95, ub);

    float obv = obj_b_all[lev];
    ob0 += obv; ob1 += obv;
    size_t arow = (size_t)(b0 + b)*8400 + aoff + p0;
    float* s0 = scores + arow*NC + ct*20;
    float out0[20], out1[20];
    #pragma unroll
    for (int n=0;n<20;n++){
        float cb = cbl[ct*20 + n];
        out0[n] = sigmoidf(acc[n][0] + cb + ob0);
        out1[n] = sigmoidf(acc[n][1] + cb + ob1);
    }
    #pragma unroll
    for (int q=0;q<5;q++){
        *(float4*)(s0 + q*4)      = *(float4*)(&out0[q*4]);
        *(float4*)(s0 + NC + q*4) = *(float4*)(&out1[q*4]);
    }
}

// ---------------------------------------------------------------------------
// Head reg + DFL + boxes, all levels. grid = (34, bc);
// block 256 = 2ct(16ch = one k-pair) x 128tp(2px).
// ---------------------------------------------------------------------------
__global__ __launch_bounds__(256) void head_reg_kernel(
    const unsigned short* __restrict__ xr,
    const float* __restrict__ reg_w_all, const float* __restrict__ reg_b_all,
    float* __restrict__ boxes, int b0)
{
    int bx = blockIdx.x;
    int lev, pb, HW, W, aoff; float sc;
    if (bx < 25){ lev=0; pb = bx<<8;      HW=6400; W=80; aoff=0;    sc=8.f;  }
    else if (bx < 32){ lev=1; pb = (bx-25)<<8; HW=1600; W=40; aoff=6400; sc=16.f; }
    else { lev=2; pb = (bx-32)<<8; HW=400;  W=20; aoff=8000; sc=32.f; }

    __shared__ __align__(16) float wr[96*32];   // [c][n]
    __shared__ float rbl[32];
    const float* reg_w = reg_w_all + (size_t)lev*32*96;
    for (int idx = threadIdx.x; idx < 96*32; idx += 256){
        int c = idx/32, n = idx & 31;
        wr[idx] = reg_w[n*96 + c];
    }
    if (threadIdx.x < 32) rbl[threadIdx.x] = reg_b_all[lev*32 + threadIdx.x];
    __syncthreads();

    int ct = threadIdx.x >> 7;
    int tp = threadIdx.x & 127;
    int p0 = pb + tp*2;
    if (p0 >= HW) return;
    int b = blockIdx.y;
    const unsigned short* xb = xr + (size_t)b*96*8400 + aoff + p0;

    float acc[16][2];
    #pragma unroll
    for (int n=0;n<16;n++){ acc[n][0]=0.f; acc[n][1]=0.f; }
    const float4* wv4 = (const float4*)wr;
    int ct4 = ct*4;

    auto body = [&](int c, unsigned int u){
        float xx = bf2f(u & 0xffffu), xy = bf2f(u >> 16);
        #pragma unroll
        for (int q=0;q<4;q++){
            float4 wv = wv4[c*8 + ct4 + q];
            #pragma unroll
            for (int k=0;k<4;k++){
                float wk = (k==0)?wv.x:(k==1)?wv.y:(k==2)?wv.z:wv.w;
                int n = q*4 + k;
                acc[n][0] = fmaf(xx, wk, acc[n][0]);
                acc[n][1] = fmaf(xy, wk, acc[n][1]);
            }
        }
    };

    unsigned int ua = *(const unsigned int*)(xb);
    unsigned int ub = *(const unsigned int*)(xb + 8400);
    #pragma unroll 4
    for (int c=0; c<94; c++){
        unsigned int un = *(const unsigned int*)(xb + (size_t)(c+2)*8400);
        body(c, ua);
        ua = ub; ub = un;
    }
    body(94, ua);
    body(95, ub);

    #pragma unroll
    for (int j=0;j<2;j++){
        int p = p0 + j;
        float l2[2];
        #pragma unroll
        for (int kk=0;kk<2;kk++){
            float t[8]; float m = -1e30f;
            #pragma unroll
            for (int r=0;r<8;r++){
                t[r] = acc[kk*8+r][j] + rbl[ct*16 + kk*8 + r];
                m = fmaxf(m, t[r]);
            }
            float den = 0.f, num = 0.f;
            #pragma unroll
            for (int r=0;r<8;r++){
                float e = __expf(t[r]-m);
                den += e; num = fmaf(e, (float)r, num);
            }
            l2[kk] = num/den * sc;
        }
        int ay_i = (lev==0) ? (p/80) : (lev==1) ? (p/40) : (p/20);
        float ax = ((float)(p - ay_i*W) + 0.5f) * sc;
        float ay = ((float)ay_i + 0.5f) * sc;
        size_t arow = (size_t)(b0 + b)*8400 + aoff + p;
        float2 r2;
        if (ct == 0){ r2.x = ax - l2[0]; r2.y = ay - l2[1]; }
        else        { r2.x = ax + l2[0]; r2.y = ay + l2[1]; }
        *(float2*)(boxes + arow*4 + ct*2) = r2;
    }
}

// ---------------------------------------------------------------------------
extern "C" void kernel_launch(void* const* d_in, const int* in_sizes, int n_in,
                              void* d_out, int out_size, void* d_ws, size_t ws_size,
                              hipStream_t stream)
{
    const float* feat[3] = {(const float*)d_in[0], (const float*)d_in[1], (const float*)d_in[2]};
    const float* primary_w = (const float*)d_in[3];
    const float* bn1_s     = (const float*)d_in[4];
    const float* bn1_b     = (const float*)d_in[5];
    const float* cheap_w   = (const float*)d_in[6];
    const float* bn2_s     = (const float*)d_in[7];
    const float* bn2_b     = (const float*)d_in[8];
    const float* cls_w     = (const float*)d_in[9];
    const float* cls_b     = (const float*)d_in[10];
    const float* obj_w     = (const float*)d_in[11];
    const float* obj_b     = (const float*)d_in[12];
    const float* reg_w     = (const float*)d_in[13];
    const float* reg_b     = (const float*)d_in[14];

    const int B = 16;
    float* boxes  = (float*)d_out;
    float* scores = (float*)d_out + (size_t)16*8400*4;

    // 4 bf16 buffers of [bc][96][8400]
    int bc = 16;
    while (bc > 1 && 4*(size_t)bc*96*8400*2 > ws_size) bc >>= 1;
    size_t perBuf = (size_t)bc*96*8400;
    unsigned short* bufA = (unsigned short*)d_ws;
    unsigned short* bufB = bufA + perBuf;
    unsigned short* bufC = bufB + perBuf;
    unsigned short* bufD = bufC + perBuf;

    const int HWs[3] = {6400, 1600, 400};

    for (int b0=0; b0<B; b0+=bc){
        const float* f0 = feat[0] + (size_t)b0*96*HWs[0];
        const float* f1 = feat[1] + (size_t)b0*96*HWs[1];
        const float* f2 = feat[2] + (size_t)b0*96*HWs[2];
        // layer 0: feats -> A (cls), C (reg); dw completes concat
        pw_kernel<1><<<dim3(34, bc, 2), 256, 0, stream>>>(
            f0, f1, f2, nullptr, nullptr, bufA, bufC,
            primary_w, bn1_s, bn1_b, 0);
        dw_kernel<<<dim3(10, 96, bc), 256, 0, stream>>>(
            bufA, bufC, cheap_w, bn2_s, bn2_b, 0);
        // layer 1: A -> B (cls), C -> D (reg)
        pw_kernel<0><<<dim3(34, bc, 2), 256, 0, stream>>>(
            nullptr, nullptr, nullptr, bufA, bufC, bufB, bufD,
            primary_w, bn1_s, bn1_b, 1);
        dw_kernel<<<dim3(10, 96, bc), 256, 0, stream>>>(
            bufB, bufD, cheap_w, bn2_s, bn2_b, 1);
        // heads
        head_cls_kernel<<<dim3(67, bc), 256, 0, stream>>>(
            bufB, cls_w, cls_b, obj_w, obj_b, scores, b0);
        head_reg_kernel<<<dim3(34, bc), 256, 0, stream>>>(
            bufD, reg_w, reg_b, boxes, b0);
    }
}

// Round 4
// 183.963 us; speedup vs baseline: 4.9432x; 1.2969x over previous
//
#include <hip/hip_runtime.h>
#include <math.h>

typedef unsigned short ushort_t;
typedef __attribute__((ext_vector_type(8))) short bf16x8;
typedef __attribute__((ext_vector_type(4))) float f32x4;

__device__ __forceinline__ float relu6f(float x){ return fminf(fmaxf(x,0.f),6.f); }
__device__ __forceinline__ float sigmoidf(float x){ return 1.f/(1.f+__expf(-x)); }
__device__ __forceinline__ float bf2f(unsigned u){ union{unsigned i; float f;}v; v.i=u<<16; return v.f; }
__device__ __forceinline__ unsigned f2bf(float f){ union{float f; unsigned i;}v; v.f=f;
    unsigned r = v.i + 0x7fff + ((v.i>>16)&1); return r>>16; }
__device__ __forceinline__ bf16x8 ldb8(const ushort_t* p){ return *reinterpret_cast<const bf16x8*>(p); }
#define MFMA(a,b,c) __builtin_amdgcn_mfma_f32_16x16x32_bf16((a),(b),(c),0,0,0)

// ---------------------------------------------------------------------------
// Weight prep (runs once): fp32 -> bf16, cls gets obj row appended + zero pad.
// pwW [4][48][96]; clsW [3][96][96] (rows 0..79 cls, 80 obj, rest 0); regW [3][32][96]
// ---------------------------------------------------------------------------
__global__ __launch_bounds__(256) void prep_kernel(
    const float* __restrict__ primary_w, const float* __restrict__ cls_w,
    const float* __restrict__ obj_w, const float* __restrict__ reg_w,
    ushort_t* __restrict__ pwW, ushort_t* __restrict__ clsW, ushort_t* __restrict__ regW)
{
    int i = blockIdx.x*256 + threadIdx.x;
    if (i < 18432) pwW[i] = (ushort_t)f2bf(primary_w[i]);
    if (i < 27648){
        int lev = i/9216, rem = i - lev*9216, row = rem/96, c = rem - row*96;
        float v = (row < 80) ? cls_w[(lev*80 + row)*96 + c]
                : (row == 80) ? obj_w[lev*96 + c] : 0.f;
        clsW[i] = (ushort_t)f2bf(v);
    }
    if (i < 9216) regW[i] = (ushort_t)f2bf(reg_w[i]);
}

// ---------------------------------------------------------------------------
// Transpose feats [b][96][HW] fp32 -> F [b][8400][96] bf16.
// grid (132, bc): bx<100 lev0, <125 lev1, else lev2 (tiles of 64 anchors).
// ---------------------------------------------------------------------------
__global__ __launch_bounds__(256) void tr_kernel(
    const float* __restrict__ f0, const float* __restrict__ f1, const float* __restrict__ f2,
    ushort_t* __restrict__ F, int b0)
{
    __shared__ float lds[64*97];
    int bx = blockIdx.x, by = blockIdx.y;
    int lev, p0, HW, aoff;
    if (bx < 100){ lev=0; p0 = bx*64;       HW=6400; aoff=0;    }
    else if (bx < 125){ lev=1; p0 = (bx-100)*64; HW=1600; aoff=6400; }
    else { lev=2; p0 = (bx-125)*64; HW=400; aoff=8000; }
    const float* f = ((lev==0)? f0 : (lev==1)? f1 : f2) + (size_t)(b0+by)*96*HW;
    for (int idx = threadIdx.x; idx < 96*64; idx += 256){
        int c = idx >> 6, p = idx & 63;
        float v = (p0 + p < HW) ? f[(size_t)c*HW + p0 + p] : 0.f;
        lds[p*97 + c] = v;
    }
    __syncthreads();
    int r = threadIdx.x & 63, q = threadIdx.x >> 6;
    if (q < 3 && p0 + r < HW){
        unsigned pk[16];
        #pragma unroll
        for (int j=0;j<16;j++){
            float a = lds[r*97 + q*32 + 2*j], b = lds[r*97 + q*32 + 2*j + 1];
            pk[j] = f2bf(a) | (f2bf(b) << 16);
        }
        ushort_t* dst = F + ((size_t)by*8400 + aoff + p0 + r)*96 + q*32;
        #pragma unroll
        for (int j=0;j<4;j++){
            uint4 u; u.x = pk[4*j]; u.y = pk[4*j+1]; u.z = pk[4*j+2]; u.w = pk[4*j+3];
            *reinterpret_cast<uint4*>(dst + j*8) = u;
        }
    }
}

// ---------------------------------------------------------------------------
// Pointwise 96->48 + BN + ReLU6 via MFMA, both branches.
// grid (66, bc, 2), block 256 (4 waves); wave = 2 anchor-tiles of 16.
// D = W(48x96) * X^T; lane holds 4 consecutive out-channels of 1 anchor.
// ---------------------------------------------------------------------------
__global__ __launch_bounds__(256) void pw_mfma(
    const ushort_t* __restrict__ Xc, const ushort_t* __restrict__ Xr,
    ushort_t* __restrict__ Oc, ushort_t* __restrict__ Or,
    const ushort_t* __restrict__ pwW,
    const float* __restrict__ bn1_s, const float* __restrict__ bn1_b, int li)
{
    int br = blockIdx.z, pl = br*2 + li;
    const ushort_t* W = pwW + (size_t)pl*48*96;
    int lane = threadIdx.x & 63, wv = threadIdx.x >> 6;
    int l15 = lane & 15, rg = lane >> 4;

    bf16x8 A[3][3];
    #pragma unroll
    for (int ot=0; ot<3; ot++)
        #pragma unroll
        for (int kt=0; kt<3; kt++)
            A[ot][kt] = ldb8(W + (size_t)(ot*16 + l15)*96 + kt*32 + rg*8);

    float sv[3][4], bv[3][4];
    #pragma unroll
    for (int ot=0; ot<3; ot++)
        #pragma unroll
        for (int j=0;j<4;j++){
            int ch = ot*16 + rg*4 + j;
            sv[ot][j] = bn1_s[pl*48 + ch];
            bv[ot][j] = bn1_b[pl*48 + ch];
        }

    const ushort_t* X = (br ? Xr : Xc) + (size_t)blockIdx.y*8400*96;
    ushort_t* O = (br ? Or : Oc) + (size_t)blockIdx.y*8400*96;
    int wg = blockIdx.x*4 + wv;

    #pragma unroll
    for (int i=0;i<2;i++){
        int t = wg*2 + i;
        if (t >= 525) break;
        int a0 = t*16;
        bf16x8 Bf[3];
        #pragma unroll
        for (int kt=0;kt<3;kt++)
            Bf[kt] = ldb8(X + (size_t)(a0 + l15)*96 + kt*32 + rg*8);
        f32x4 acc[3];
        #pragma unroll
        for (int ot=0;ot<3;ot++){ acc[ot][0]=0.f; acc[ot][1]=0.f; acc[ot][2]=0.f; acc[ot][3]=0.f; }
        #pragma unroll
        for (int kt=0;kt<3;kt++)
            #pragma unroll
            for (int ot=0;ot<3;ot++)
                acc[ot] = MFMA(A[ot][kt], Bf[kt], acc[ot]);
        ushort_t* orow = O + (size_t)(a0 + l15)*96;
        #pragma unroll
        for (int ot=0;ot<3;ot++){
            uint2 u;
            u.x = f2bf(relu6f(fmaf(acc[ot][0], sv[ot][0], bv[ot][0])))
               | (f2bf(relu6f(fmaf(acc[ot][1], sv[ot][1], bv[ot][1]))) << 16);
            u.y = f2bf(relu6f(fmaf(acc[ot][2], sv[ot][2], bv[ot][2])))
               | (f2bf(relu6f(fmaf(acc[ot][3], sv[ot][3], bv[ot][3]))) << 16);
            *reinterpret_cast<uint2*>(orow + ot*16 + rg*4) = u;
        }
    }
}

// ---------------------------------------------------------------------------
// Depthwise 3x3 + BN + ReLU6 in [a][96] layout. Reads ch[0,48), writes [48,96).
// grid (132, bc, 2), block 384 = 6 waves; wave = ch-slice of 8 (uniform),
// lane = anchor. Weights broadcast from LDS.
// ---------------------------------------------------------------------------
__global__ __launch_bounds__(384) void dw_kernel(
    ushort_t* __restrict__ Bc, ushort_t* __restrict__ Br,
    const float* __restrict__ cheap_w,
    const float* __restrict__ bn2_s, const float* __restrict__ bn2_b, int li)
{
    __shared__ float wsm[432], s2sm[48], b2sm[48];
    int br = blockIdx.z, pl = br*2 + li;
    for (int i = threadIdx.x; i < 432; i += 384) wsm[i] = cheap_w[pl*432 + i];
    if (threadIdx.x < 48){
        s2sm[threadIdx.x] = bn2_s[pl*48 + threadIdx.x];
        b2sm[threadIdx.x] = bn2_b[pl*48 + threadIdx.x];
    }
    __syncthreads();

    int s8 = (threadIdx.x >> 6) * 8;
    int a  = blockIdx.x*64 + (threadIdx.x & 63);
    if (a >= 8400) return;
    int lev, W, aoff;
    if (a < 6400){ lev=0; W=80; aoff=0; }
    else if (a < 8000){ lev=1; W=40; aoff=6400; }
    else { lev=2; W=20; aoff=8000; }
    int p = a - aoff;
    int h = (lev==0) ? p/80 : (lev==1) ? p/40 : p/20;
    int x = p - h*W;

    ushort_t* rowp = (br ? Br : Bc) + ((size_t)blockIdx.y*8400 + a)*96;
    float acc[8];
    #pragma unroll
    for (int c=0;c<8;c++) acc[c] = 0.f;

    #pragma unroll
    for (int dy=-1; dy<=1; dy++){
        int hh = h + dy;
        if ((unsigned)hh >= (unsigned)W) continue;   // H == W
        #pragma unroll
        for (int dx=-1; dx<=1; dx++){
            int xx = x + dx;
            if ((unsigned)xx >= (unsigned)W) continue;
            const ushort_t* rp = rowp + (ptrdiff_t)(dy*W + dx)*96 + s8;
            uint4 u = *reinterpret_cast<const uint4*>(rp);
            int tap = (dy+1)*3 + (dx+1);
            const float* wt = &wsm[s8*9 + tap];
            acc[0] = fmaf(bf2f(u.x & 0xffffu), wt[0],  acc[0]);
            acc[1] = fmaf(bf2f(u.x >> 16),     wt[9],  acc[1]);
            acc[2] = fmaf(bf2f(u.y & 0xffffu), wt[18], acc[2]);
            acc[3] = fmaf(bf2f(u.y >> 16),     wt[27], acc[3]);
            acc[4] = fmaf(bf2f(u.z & 0xffffu), wt[36], acc[4]);
            acc[5] = fmaf(bf2f(u.z >> 16),     wt[45], acc[5]);
            acc[6] = fmaf(bf2f(u.w & 0xffffu), wt[54], acc[6]);
            acc[7] = fmaf(bf2f(u.w >> 16),     wt[63], acc[7]);
        }
    }
    uint4 o;
    o.x = f2bf(relu6f(fmaf(acc[0], s2sm[s8+0], b2sm[s8+0])))
       | (f2bf(relu6f(fmaf(acc[1], s2sm[s8+1], b2sm[s8+1]))) << 16);
    o.y = f2bf(relu6f(fmaf(acc[2], s2sm[s8+2], b2sm[s8+2])))
       | (f2bf(relu6f(fmaf(acc[3], s2sm[s8+3], b2sm[s8+3]))) << 16);
    o.z = f2bf(relu6f(fmaf(acc[4], s2sm[s8+4], b2sm[s8+4])))
       | (f2bf(relu6f(fmaf(acc[5], s2sm[s8+5], b2sm[s8+5]))) << 16);
    o.w = f2bf(relu6f(fmaf(acc[6], s2sm[s8+6], b2sm[s8+6])))
       | (f2bf(relu6f(fmaf(acc[7], s2sm[s8+7], b2sm[s8+7]))) << 16);
    *reinterpret_cast<uint4*>(rowp + 48 + s8) = o;
}

// ---------------------------------------------------------------------------
// Head cls+obj via MFMA. N = 96 (80 cls + obj@80 + pad). grid (66, bc).
// ---------------------------------------------------------------------------
__global__ __launch_bounds__(256) void head_cls_mfma(
    const ushort_t* __restrict__ Xc, const ushort_t* __restrict__ clsW,
    const float* __restrict__ cls_b_all, const float* __restrict__ obj_b_all,
    float* __restrict__ scores, int b0)
{
    int lane = threadIdx.x & 63, wv = threadIdx.x >> 6;
    int l15 = lane & 15, rg = lane >> 4;
    const ushort_t* X = Xc + (size_t)blockIdx.y*8400*96;
    float* sbase = scores + (size_t)(b0 + blockIdx.y)*8400*80;
    int wg = blockIdx.x*4 + wv;

    bf16x8 A[6][3];
    float cb[5][4];
    float obv = 0.f;
    int curlev = -1;

    for (int i=0;i<2;i++){
        int t = wg*2 + i;
        if (t >= 525) break;
        int lev = (t < 400) ? 0 : (t < 500) ? 1 : 2;
        if (lev != curlev){
            curlev = lev;
            const ushort_t* Wl = clsW + (size_t)lev*96*96;
            #pragma unroll
            for (int ot=0; ot<6; ot++)
                #pragma unroll
                for (int kt=0; kt<3; kt++)
                    A[ot][kt] = ldb8(Wl + (size_t)(ot*16 + l15)*96 + kt*32 + rg*8);
            #pragma unroll
            for (int ot=0; ot<5; ot++)
                #pragma unroll
                for (int j=0;j<4;j++)
                    cb[ot][j] = cls_b_all[lev*80 + ot*16 + rg*4 + j];
            obv = obj_b_all[lev];
        }
        int a0 = t*16;
        bf16x8 Bf[3];
        #pragma unroll
        for (int kt=0;kt<3;kt++)
            Bf[kt] = ldb8(X + (size_t)(a0 + l15)*96 + kt*32 + rg*8);
        f32x4 acc[6];
        #pragma unroll
        for (int ot=0;ot<6;ot++){ acc[ot][0]=0.f; acc[ot][1]=0.f; acc[ot][2]=0.f; acc[ot][3]=0.f; }
        #pragma unroll
        for (int kt=0;kt<3;kt++)
            #pragma unroll
            for (int ot=0;ot<6;ot++)
                acc[ot] = MFMA(A[ot][kt], Bf[kt], acc[ot]);

        float objp = acc[5][0];                  // row 80 lives in rg==0 lanes
        float objv = __shfl(objp, l15) + obv;    // broadcast to all rgs of this anchor
        float* srow = sbase + (size_t)(a0 + l15)*80;
        #pragma unroll
        for (int ot=0;ot<5;ot++){
            f32x4 o;
            #pragma unroll
            for (int j=0;j<4;j++)
                o[j] = sigmoidf(acc[ot][j] + cb[ot][j] + objv);
            *reinterpret_cast<f32x4*>(srow + ot*16 + rg*4) = o;
        }
    }
}

// ---------------------------------------------------------------------------
// Head reg via MFMA + in-register DFL + boxes. grid (66, bc).
// lane ch n = ot*16+rg*4+j; k = ot*2+(rg>>1); r = (rg&1)*4+j.
// ---------------------------------------------------------------------------
__global__ __launch_bounds__(256) void head_reg_mfma(
    const ushort_t* __restrict__ Xr, const ushort_t* __restrict__ regW,
    const float* __restrict__ reg_b_all, float* __restrict__ boxes, int b0)
{
    int lane = threadIdx.x & 63, wv = threadIdx.x >> 6;
    int l15 = lane & 15, rg = lane >> 4;
    const ushort_t* X = Xr + (size_t)blockIdx.y*8400*96;
    float* bbase = boxes + (size_t)(b0 + blockIdx.y)*8400*4;
    int wg = blockIdx.x*4 + wv;

    bf16x8 A[2][3];
    float rb[2][4];
    float sc = 8.f; int aoff = 0, Wd = 80, curlev = -1;

    for (int i=0;i<2;i++){
        int t = wg*2 + i;
        if (t >= 525) break;
        int lev = (t < 400) ? 0 : (t < 500) ? 1 : 2;
        if (lev != curlev){
            curlev = lev;
            const ushort_t* Wl = regW + (size_t)lev*32*96;
            #pragma unroll
            for (int ot=0; ot<2; ot++)
                #pragma unroll
                for (int kt=0; kt<3; kt++)
                    A[ot][kt] = ldb8(Wl + (size_t)(ot*16 + l15)*96 + kt*32 + rg*8);
            #pragma unroll
            for (int ot=0; ot<2; ot++)
                #pragma unroll
                for (int j=0;j<4;j++)
                    rb[ot][j] = reg_b_all[lev*32 + ot*16 + rg*4 + j];
            sc   = (lev==0) ? 8.f : (lev==1) ? 16.f : 32.f;
            aoff = (lev==0) ? 0   : (lev==1) ? 6400 : 8000;
            Wd   = (lev==0) ? 80  : (lev==1) ? 40   : 20;
        }
        int a0 = t*16;
        bf16x8 Bf[3];
        #pragma unroll
        for (int kt=0;kt<3;kt++)
            Bf[kt] = ldb8(X + (size_t)(a0 + l15)*96 + kt*32 + rg*8);
        f32x4 acc[2];
        #pragma unroll
        for (int ot=0;ot<2;ot++){ acc[ot][0]=0.f; acc[ot][1]=0.f; acc[ot][2]=0.f; acc[ot][3]=0.f; }
        #pragma unroll
        for (int kt=0;kt<3;kt++)
            #pragma unroll
            for (int ot=0;ot<2;ot++)
                acc[ot] = MFMA(A[ot][kt], Bf[kt], acc[ot]);

        // DFL softmax-expectation, 8-bin groups split across rg-pairs
        float rbase = (float)((rg & 1) * 4);
        float lv[2];
        #pragma unroll
        for (int ot=0;ot<2;ot++){
            float tv[4];
            #pragma unroll
            for (int j=0;j<4;j++) tv[j] = acc[ot][j] + rb[ot][j];
            float m = fmaxf(fmaxf(tv[0],tv[1]), fmaxf(tv[2],tv[3]));
            m = fmaxf(m, __shfl_xor(m, 16));
            float se = 0.f, ne = 0.f;
            #pragma unroll
            for (int j=0;j<4;j++){
                float e = __expf(tv[j] - m);
                se += e; ne = fmaf(e, rbase + (float)j, ne);
            }
            float den = se + __shfl_xor(se, 16);
            float num = ne + __shfl_xor(ne, 16);
            lv[ot] = num / den * sc;
        }
        int a_img = a0 + l15;
        int p = a_img - aoff;
        int hh = (curlev==0) ? p/80 : (curlev==1) ? p/40 : p/20;
        int xx = p - hh*Wd;
        float ax = (xx + 0.5f)*sc, ay = (hh + 0.5f)*sc;
        float v0 = ax - lv[0];   // x1 (valid rg 0/1: k0=left)
        float v1 = ax + lv[1];   // x2 (k2=right)
        float w0 = ay - lv[0];   // y1 (valid rg 2/3: k1=top)
        float w1 = ay + lv[1];   // y2 (k3=bottom)
        float y1g = __shfl_xor(w0, 32);
        float y2g = __shfl_xor(w1, 32);
        if (lane < 16){
            f32x4 o; o[0] = v0; o[1] = y1g; o[2] = v1; o[3] = y2g;
            *reinterpret_cast<f32x4*>(bbase + (size_t)a_img*4) = o;
        }
    }
}

// ---------------------------------------------------------------------------
extern "C" void kernel_launch(void* const* d_in, const int* in_sizes, int n_in,
                              void* d_out, int out_size, void* d_ws, size_t ws_size,
                              hipStream_t stream)
{
    const float* f0        = (const float*)d_in[0];
    const float* f1        = (const float*)d_in[1];
    const float* f2        = (const float*)d_in[2];
    const float* primary_w = (const float*)d_in[3];
    const float* bn1_s     = (const float*)d_in[4];
    const float* bn1_b     = (const float*)d_in[5];
    const float* cheap_w   = (const float*)d_in[6];
    const float* bn2_s     = (const float*)d_in[7];
    const float* bn2_b     = (const float*)d_in[8];
    const float* cls_w     = (const float*)d_in[9];
    const float* cls_b     = (const float*)d_in[10];
    const float* obj_w     = (const float*)d_in[11];
    const float* obj_b     = (const float*)d_in[12];
    const float* reg_w     = (const float*)d_in[13];
    const float* reg_b     = (const float*)d_in[14];

    const int B = 16;
    float* boxes  = (float*)d_out;
    float* scores = boxes + (size_t)16*8400*4;

    ushort_t* pwW  = (ushort_t*)d_ws;
    ushort_t* clsW = pwW + 18432;
    ushort_t* regW = clsW + 27648;
    ushort_t* bufs = regW + 9216;          // 55296 ushorts = 110592 B
    size_t used0 = (size_t)55296*2;

    int bc = 16;
    while (bc > 1 && used0 + 5*(size_t)bc*8400*96*2 > ws_size) bc >>= 1;
    size_t perBuf = (size_t)bc*8400*96;
    ushort_t* F  = bufs;
    ushort_t* C0 = F  + perBuf;
    ushort_t* R0 = C0 + perBuf;
    ushort_t* C1 = R0 + perBuf;
    ushort_t* R1 = C1 + perBuf;

    prep_kernel<<<108, 256, 0, stream>>>(primary_w, cls_w, obj_w, reg_w, pwW, clsW, regW);

    for (int b0 = 0; b0 < B; b0 += bc){
        tr_kernel<<<dim3(132, bc), 256, 0, stream>>>(f0, f1, f2, F, b0);
        pw_mfma<<<dim3(66, bc, 2), 256, 0, stream>>>(F, F, C0, R0, pwW, bn1_s, bn1_b, 0);
        dw_kernel<<<dim3(132, bc, 2), 384, 0, stream>>>(C0, R0, cheap_w, bn2_s, bn2_b, 0);
        pw_mfma<<<dim3(66, bc, 2), 256, 0, stream>>>(C0, R0, C1, R1, pwW, bn1_s, bn1_b, 1);
        dw_kernel<<<dim3(132, bc, 2), 384, 0, stream>>>(C1, R1, cheap_w, bn2_s, bn2_b, 1);
        head_cls_mfma<<<dim3(66, bc), 256, 0, stream>>>(C1, clsW, cls_b, obj_b, scores, b0);
        head_reg_mfma<<<dim3(66, bc), 256, 0, stream>>>(R1, regW, reg_b, boxes, b0);
    }
}

// Round 5
// 166.181 us; speedup vs baseline: 5.4721x; 1.1070x over previous
//
#include <hip/hip_runtime.h>
#include <math.h>

typedef unsigned short ushort_t;
typedef __attribute__((ext_vector_type(8))) short bf16x8;
typedef __attribute__((ext_vector_type(4))) float f32x4;

__device__ __forceinline__ float relu6f(float x){ return fminf(fmaxf(x,0.f),6.f); }
__device__ __forceinline__ float sigmoidf(float x){ return 1.f/(1.f+__expf(-x)); }
__device__ __forceinline__ float bf2f(unsigned u){ union{unsigned i; float f;}v; v.i=u<<16; return v.f; }
__device__ __forceinline__ unsigned f2bf(float f){ union{float f; unsigned i;}v; v.f=f;
    unsigned r = v.i + 0x7fff + ((v.i>>16)&1); return r>>16; }
__device__ __forceinline__ bf16x8 ldb8(const ushort_t* p){ return *reinterpret_cast<const bf16x8*>(p); }
#define MFMA(a,b,c) __builtin_amdgcn_mfma_f32_16x16x32_bf16((a),(b),(c),0,0,0)

// ---------------------------------------------------------------------------
// Weight prep (runs once): fp32 -> bf16, cls gets obj row appended + zero pad.
// pwW [4][48][96]; clsW [3][96][96] (rows 0..79 cls, 80 obj, rest 0); regW [3][32][96]
// ---------------------------------------------------------------------------
__global__ __launch_bounds__(256) void prep_kernel(
    const float* __restrict__ primary_w, const float* __restrict__ cls_w,
    const float* __restrict__ obj_w, const float* __restrict__ reg_w,
    ushort_t* __restrict__ pwW, ushort_t* __restrict__ clsW, ushort_t* __restrict__ regW)
{
    int i = blockIdx.x*256 + threadIdx.x;
    if (i < 18432) pwW[i] = (ushort_t)f2bf(primary_w[i]);
    if (i < 27648){
        int lev = i/9216, rem = i - lev*9216, row = rem/96, c = rem - row*96;
        float v = (row < 80) ? cls_w[(lev*80 + row)*96 + c]
                : (row == 80) ? obj_w[lev*96 + c] : 0.f;
        clsW[i] = (ushort_t)f2bf(v);
    }
    if (i < 9216) regW[i] = (ushort_t)f2bf(reg_w[i]);
}

// ---------------------------------------------------------------------------
// Transpose feats [b][96][HW] fp32 -> F [b][8400][96] bf16.
// grid (132, bc): bx<100 lev0, <125 lev1, else lev2 (tiles of 64 anchors).
// ---------------------------------------------------------------------------
__global__ __launch_bounds__(256) void tr_kernel(
    const float* __restrict__ f0, const float* __restrict__ f1, const float* __restrict__ f2,
    ushort_t* __restrict__ F, int b0)
{
    __shared__ float lds[64*97];
    int bx = blockIdx.x, by = blockIdx.y;
    int lev, p0, HW, aoff;
    if (bx < 100){ lev=0; p0 = bx*64;       HW=6400; aoff=0;    }
    else if (bx < 125){ lev=1; p0 = (bx-100)*64; HW=1600; aoff=6400; }
    else { lev=2; p0 = (bx-125)*64; HW=400; aoff=8000; }
    const float* f = ((lev==0)? f0 : (lev==1)? f1 : f2) + (size_t)(b0+by)*96*HW;
    for (int idx = threadIdx.x; idx < 96*64; idx += 256){
        int c = idx >> 6, p = idx & 63;
        float v = (p0 + p < HW) ? f[(size_t)c*HW + p0 + p] : 0.f;
        lds[p*97 + c] = v;
    }
    __syncthreads();
    int r = threadIdx.x & 63, q = threadIdx.x >> 6;
    if (q < 3 && p0 + r < HW){
        unsigned pk[16];
        #pragma unroll
        for (int j=0;j<16;j++){
            float a = lds[r*97 + q*32 + 2*j], b = lds[r*97 + q*32 + 2*j + 1];
            pk[j] = f2bf(a) | (f2bf(b) << 16);
        }
        ushort_t* dst = F + ((size_t)by*8400 + aoff + p0 + r)*96 + q*32;
        #pragma unroll
        for (int j=0;j<4;j++){
            uint4 u; u.x = pk[4*j]; u.y = pk[4*j+1]; u.z = pk[4*j+2]; u.w = pk[4*j+3];
            *reinterpret_cast<uint4*>(dst + j*8) = u;
        }
    }
}

// ---------------------------------------------------------------------------
// Pointwise 96->48 + BN + ReLU6 via MFMA, both branches.
// grid (66, bc, 2), block 256 (4 waves); wave = 2 anchor-tiles of 16.
// D = W(48x96) * X^T; lane holds 4 consecutive out-channels of 1 anchor.
// ---------------------------------------------------------------------------
__global__ __launch_bounds__(256) void pw_mfma(
    const ushort_t* __restrict__ Xc, const ushort_t* __restrict__ Xr,
    ushort_t* __restrict__ Oc, ushort_t* __restrict__ Or,
    const ushort_t* __restrict__ pwW,
    const float* __restrict__ bn1_s, const float* __restrict__ bn1_b, int li)
{
    int br = blockIdx.z, pl = br*2 + li;
    const ushort_t* W = pwW + (size_t)pl*48*96;
    int lane = threadIdx.x & 63, wv = threadIdx.x >> 6;
    int l15 = lane & 15, rg = lane >> 4;

    bf16x8 A[3][3];
    #pragma unroll
    for (int ot=0; ot<3; ot++)
        #pragma unroll
        for (int kt=0; kt<3; kt++)
            A[ot][kt] = ldb8(W + (size_t)(ot*16 + l15)*96 + kt*32 + rg*8);

    float sv[3][4], bv[3][4];
    #pragma unroll
    for (int ot=0; ot<3; ot++)
        #pragma unroll
        for (int j=0;j<4;j++){
            int ch = ot*16 + rg*4 + j;
            sv[ot][j] = bn1_s[pl*48 + ch];
            bv[ot][j] = bn1_b[pl*48 + ch];
        }

    const ushort_t* X = (br ? Xr : Xc) + (size_t)blockIdx.y*8400*96;
    ushort_t* O = (br ? Or : Oc) + (size_t)blockIdx.y*8400*96;
    int wg = blockIdx.x*4 + wv;

    #pragma unroll
    for (int i=0;i<2;i++){
        int t = wg*2 + i;
        if (t >= 525) break;
        int a0 = t*16;
        bf16x8 Bf[3];
        #pragma unroll
        for (int kt=0;kt<3;kt++)
            Bf[kt] = ldb8(X + (size_t)(a0 + l15)*96 + kt*32 + rg*8);
        f32x4 acc[3];
        #pragma unroll
        for (int ot=0;ot<3;ot++){ acc[ot][0]=0.f; acc[ot][1]=0.f; acc[ot][2]=0.f; acc[ot][3]=0.f; }
        #pragma unroll
        for (int kt=0;kt<3;kt++)
            #pragma unroll
            for (int ot=0;ot<3;ot++)
                acc[ot] = MFMA(A[ot][kt], Bf[kt], acc[ot]);
        ushort_t* orow = O + (size_t)(a0 + l15)*96;
        #pragma unroll
        for (int ot=0;ot<3;ot++){
            uint2 u;
            u.x = f2bf(relu6f(fmaf(acc[ot][0], sv[ot][0], bv[ot][0])))
               | (f2bf(relu6f(fmaf(acc[ot][1], sv[ot][1], bv[ot][1]))) << 16);
            u.y = f2bf(relu6f(fmaf(acc[ot][2], sv[ot][2], bv[ot][2])))
               | (f2bf(relu6f(fmaf(acc[ot][3], sv[ot][3], bv[ot][3]))) << 16);
            *reinterpret_cast<uint2*>(orow + ot*16 + rg*4) = u;
        }
    }
}

// ---------------------------------------------------------------------------
// Depthwise 3x3 + BN + ReLU6, [a][96] layout. Reads ch[0,48), writes [48,96).
// grid (33, bc, 2), block 384 = 6 waves. Thread = 8-ch slice (wave-uniform)
// x 4 consecutive anchors (same row). 18 predicated uint4 loads, converted
// once, reused across 3 taps (288 FMA). Weights/BN via wave-uniform scalar
// loads (no LDS).
// ---------------------------------------------------------------------------
__global__ __launch_bounds__(384) void dw_kernel(
    ushort_t* __restrict__ Bc, ushort_t* __restrict__ Br,
    const float* __restrict__ cheap_w,
    const float* __restrict__ bn2_s, const float* __restrict__ bn2_b, int li)
{
    int br = blockIdx.z, pl = br*2 + li;
    int s8 = __builtin_amdgcn_readfirstlane(((int)threadIdx.x >> 6) * 8);

    int qa = blockIdx.x*64 + ((int)threadIdx.x & 63);
    int a0 = qa*4;
    if (a0 >= 8400) return;
    int lev, W;
    int aoff;
    if (a0 < 6400){ lev=0; W=80; aoff=0; }
    else if (a0 < 8000){ lev=1; W=40; aoff=6400; }
    else { lev=2; W=20; aoff=8000; }
    int p = a0 - aoff;
    int h = (lev==0) ? p/80 : (lev==1) ? p/40 : p/20;
    int x0 = p - h*W;                 // multiple of 4; anchors a0..a0+3 same row

    ushort_t* base = (br ? Br : Bc) + ((size_t)blockIdx.y*8400 + a0)*96 + s8;

    float acc[4][8];
    #pragma unroll
    for (int j=0;j<4;j++)
        #pragma unroll
        for (int c=0;c<8;c++) acc[j][c] = 0.f;

    #pragma unroll
    for (int dy=-1; dy<=1; dy++){
        int hh = h + dy;
        bool rv = (unsigned)hh < (unsigned)W;    // H == W (square levels)
        float xv[6][8];
        #pragma unroll
        for (int i=0;i<6;i++){
            int px = x0 + i - 1;
            bool v = rv && (px >= 0) && (px < W);
            uint4 u = make_uint4(0u,0u,0u,0u);
            if (v) u = *reinterpret_cast<const uint4*>(base + (ptrdiff_t)(dy*W + i - 1)*96);
            xv[i][0]=bf2f(u.x&0xffffu); xv[i][1]=bf2f(u.x>>16);
            xv[i][2]=bf2f(u.y&0xffffu); xv[i][3]=bf2f(u.y>>16);
            xv[i][4]=bf2f(u.z&0xffffu); xv[i][5]=bf2f(u.z>>16);
            xv[i][6]=bf2f(u.w&0xffffu); xv[i][7]=bf2f(u.w>>16);
        }
        #pragma unroll
        for (int c=0;c<8;c++){
            // wave-uniform indices -> scalar loads (SGPR operands in the FMAs)
            float w0 = cheap_w[(pl*48 + s8 + c)*9 + (dy+1)*3 + 0];
            float w1 = cheap_w[(pl*48 + s8 + c)*9 + (dy+1)*3 + 1];
            float w2 = cheap_w[(pl*48 + s8 + c)*9 + (dy+1)*3 + 2];
            #pragma unroll
            for (int j=0;j<4;j++)
                acc[j][c] = fmaf(xv[j][c], w0,
                            fmaf(xv[j+1][c], w1,
                            fmaf(xv[j+2][c], w2, acc[j][c])));
        }
    }

    float s2v[8], b2v[8];
    #pragma unroll
    for (int c=0;c<8;c++){
        s2v[c] = bn2_s[pl*48 + s8 + c];
        b2v[c] = bn2_b[pl*48 + s8 + c];
    }
    #pragma unroll
    for (int j=0;j<4;j++){
        uint4 o;
        o.x = f2bf(relu6f(fmaf(acc[j][0], s2v[0], b2v[0])))
           | (f2bf(relu6f(fmaf(acc[j][1], s2v[1], b2v[1]))) << 16);
        o.y = f2bf(relu6f(fmaf(acc[j][2], s2v[2], b2v[2])))
           | (f2bf(relu6f(fmaf(acc[j][3], s2v[3], b2v[3]))) << 16);
        o.z = f2bf(relu6f(fmaf(acc[j][4], s2v[4], b2v[4])))
           | (f2bf(relu6f(fmaf(acc[j][5], s2v[5], b2v[5]))) << 16);
        o.w = f2bf(relu6f(fmaf(acc[j][6], s2v[6], b2v[6])))
           | (f2bf(relu6f(fmaf(acc[j][7], s2v[7], b2v[7]))) << 16);
        *reinterpret_cast<uint4*>(base + j*96 + 48) = o;
    }
}

// ---------------------------------------------------------------------------
// Head cls+obj via MFMA. N = 96 (80 cls + obj@80 + pad). grid (66, bc).
// ---------------------------------------------------------------------------
__global__ __launch_bounds__(256) void head_cls_mfma(
    const ushort_t* __restrict__ Xc, const ushort_t* __restrict__ clsW,
    const float* __restrict__ cls_b_all, const float* __restrict__ obj_b_all,
    float* __restrict__ scores, int b0)
{
    int lane = threadIdx.x & 63, wv = threadIdx.x >> 6;
    int l15 = lane & 15, rg = lane >> 4;
    const ushort_t* X = Xc + (size_t)blockIdx.y*8400*96;
    float* sbase = scores + (size_t)(b0 + blockIdx.y)*8400*80;
    int wg = blockIdx.x*4 + wv;

    bf16x8 A[6][3];
    float cb[5][4];
    float obv = 0.f;
    int curlev = -1;

    for (int i=0;i<2;i++){
        int t = wg*2 + i;
        if (t >= 525) break;
        int lev = (t < 400) ? 0 : (t < 500) ? 1 : 2;
        if (lev != curlev){
            curlev = lev;
            const ushort_t* Wl = clsW + (size_t)lev*96*96;
            #pragma unroll
            for (int ot=0; ot<6; ot++)
                #pragma unroll
                for (int kt=0; kt<3; kt++)
                    A[ot][kt] = ldb8(Wl + (size_t)(ot*16 + l15)*96 + kt*32 + rg*8);
            #pragma unroll
            for (int ot=0; ot<5; ot++)
                #pragma unroll
                for (int j=0;j<4;j++)
                    cb[ot][j] = cls_b_all[lev*80 + ot*16 + rg*4 + j];
            obv = obj_b_all[lev];
        }
        int a0 = t*16;
        bf16x8 Bf[3];
        #pragma unroll
        for (int kt=0;kt<3;kt++)
            Bf[kt] = ldb8(X + (size_t)(a0 + l15)*96 + kt*32 + rg*8);
        f32x4 acc[6];
        #pragma unroll
        for (int ot=0;ot<6;ot++){ acc[ot][0]=0.f; acc[ot][1]=0.f; acc[ot][2]=0.f; acc[ot][3]=0.f; }
        #pragma unroll
        for (int kt=0;kt<3;kt++)
            #pragma unroll
            for (int ot=0;ot<6;ot++)
                acc[ot] = MFMA(A[ot][kt], Bf[kt], acc[ot]);

        float objp = acc[5][0];                  // row 80 lives in rg==0 lanes
        float objv = __shfl(objp, l15) + obv;    // broadcast to all rgs of this anchor
        float* srow = sbase + (size_t)(a0 + l15)*80;
        #pragma unroll
        for (int ot=0;ot<5;ot++){
            f32x4 o;
            #pragma unroll
            for (int j=0;j<4;j++)
                o[j] = sigmoidf(acc[ot][j] + cb[ot][j] + objv);
            *reinterpret_cast<f32x4*>(srow + ot*16 + rg*4) = o;
        }
    }
}

// ---------------------------------------------------------------------------
// Head reg via MFMA + in-register DFL + boxes. grid (66, bc).
// lane ch n = ot*16+rg*4+j; k = ot*2+(rg>>1); r = (rg&1)*4+j.
// ---------------------------------------------------------------------------
__global__ __launch_bounds__(256) void head_reg_mfma(
    const ushort_t* __restrict__ Xr, const ushort_t* __restrict__ regW,
    const float* __restrict__ reg_b_all, float* __restrict__ boxes, int b0)
{
    int lane = threadIdx.x & 63, wv = threadIdx.x >> 6;
    int l15 = lane & 15, rg = lane >> 4;
    const ushort_t* X = Xr + (size_t)blockIdx.y*8400*96;
    float* bbase = boxes + (size_t)(b0 + blockIdx.y)*8400*4;
    int wg = blockIdx.x*4 + wv;

    bf16x8 A[2][3];
    float rb[2][4];
    float sc = 8.f; int aoff = 0, Wd = 80, curlev = -1;

    for (int i=0;i<2;i++){
        int t = wg*2 + i;
        if (t >= 525) break;
        int lev = (t < 400) ? 0 : (t < 500) ? 1 : 2;
        if (lev != curlev){
            curlev = lev;
            const ushort_t* Wl = regW + (size_t)lev*32*96;
            #pragma unroll
            for (int ot=0; ot<2; ot++)
                #pragma unroll
                for (int kt=0; kt<3; kt++)
                    A[ot][kt] = ldb8(Wl + (size_t)(ot*16 + l15)*96 + kt*32 + rg*8);
            #pragma unroll
            for (int ot=0; ot<2; ot++)
                #pragma unroll
                for (int j=0;j<4;j++)
                    rb[ot][j] = reg_b_all[lev*32 + ot*16 + rg*4 + j];
            sc   = (lev==0) ? 8.f : (lev==1) ? 16.f : 32.f;
            aoff = (lev==0) ? 0   : (lev==1) ? 6400 : 8000;
            Wd   = (lev==0) ? 80  : (lev==1) ? 40   : 20;
        }
        int a0 = t*16;
        bf16x8 Bf[3];
        #pragma unroll
        for (int kt=0;kt<3;kt++)
            Bf[kt] = ldb8(X + (size_t)(a0 + l15)*96 + kt*32 + rg*8);
        f32x4 acc[2];
        #pragma unroll
        for (int ot=0;ot<2;ot++){ acc[ot][0]=0.f; acc[ot][1]=0.f; acc[ot][2]=0.f; acc[ot][3]=0.f; }
        #pragma unroll
        for (int kt=0;kt<3;kt++)
            #pragma unroll
            for (int ot=0;ot<2;ot++)
                acc[ot] = MFMA(A[ot][kt], Bf[kt], acc[ot]);

        // DFL softmax-expectation, 8-bin groups split across rg-pairs
        float rbase = (float)((rg & 1) * 4);
        float lv[2];
        #pragma unroll
        for (int ot=0;ot<2;ot++){
            float tv[4];
            #pragma unroll
            for (int j=0;j<4;j++) tv[j] = acc[ot][j] + rb[ot][j];
            float m = fmaxf(fmaxf(tv[0],tv[1]), fmaxf(tv[2],tv[3]));
            m = fmaxf(m, __shfl_xor(m, 16));
            float se = 0.f, ne = 0.f;
            #pragma unroll
            for (int j=0;j<4;j++){
                float e = __expf(tv[j] - m);
                se += e; ne = fmaf(e, rbase + (float)j, ne);
            }
            float den = se + __shfl_xor(se, 16);
            float num = ne + __shfl_xor(ne, 16);
            lv[ot] = num / den * sc;
        }
        int a_img = a0 + l15;
        int p = a_img - aoff;
        int hh = (curlev==0) ? p/80 : (curlev==1) ? p/40 : p/20;
        int xx = p - hh*Wd;
        float ax = (xx + 0.5f)*sc, ay = (hh + 0.5f)*sc;
        float v0 = ax - lv[0];   // x1 (valid rg 0/1: k0=left)
        float v1 = ax + lv[1];   // x2 (k2=right)
        float w0 = ay - lv[0];   // y1 (valid rg 2/3: k1=top)
        float w1 = ay + lv[1];   // y2 (k3=bottom)
        float y1g = __shfl_xor(w0, 32);
        float y2g = __shfl_xor(w1, 32);
        if (lane < 16){
            f32x4 o; o[0] = v0; o[1] = y1g; o[2] = v1; o[3] = y2g;
            *reinterpret_cast<f32x4*>(bbase + (size_t)a_img*4) = o;
        }
    }
}

// ---------------------------------------------------------------------------
extern "C" void kernel_launch(void* const* d_in, const int* in_sizes, int n_in,
                              void* d_out, int out_size, void* d_ws, size_t ws_size,
                              hipStream_t stream)
{
    const float* f0        = (const float*)d_in[0];
    const float* f1        = (const float*)d_in[1];
    const float* f2        = (const float*)d_in[2];
    const float* primary_w = (const float*)d_in[3];
    const float* bn1_s     = (const float*)d_in[4];
    const float* bn1_b     = (const float*)d_in[5];
    const float* cheap_w   = (const float*)d_in[6];
    const float* bn2_s     = (const float*)d_in[7];
    const float* bn2_b     = (const float*)d_in[8];
    const float* cls_w     = (const float*)d_in[9];
    const float* cls_b     = (const float*)d_in[10];
    const float* obj_w     = (const float*)d_in[11];
    const float* obj_b     = (const float*)d_in[12];
    const float* reg_w     = (const float*)d_in[13];
    const float* reg_b     = (const float*)d_in[14];

    const int B = 16;
    float* boxes  = (float*)d_out;
    float* scores = boxes + (size_t)16*8400*4;

    ushort_t* pwW  = (ushort_t*)d_ws;
    ushort_t* clsW = pwW + 18432;
    ushort_t* regW = clsW + 27648;
    ushort_t* bufs = regW + 9216;          // 55296 ushorts = 110592 B
    size_t used0 = (size_t)55296*2;

    int bc = 16;
    while (bc > 1 && used0 + 5*(size_t)bc*8400*96*2 > ws_size) bc >>= 1;
    size_t perBuf = (size_t)bc*8400*96;
    ushort_t* F  = bufs;
    ushort_t* C0 = F  + perBuf;
    ushort_t* R0 = C0 + perBuf;
    ushort_t* C1 = R0 + perBuf;
    ushort_t* R1 = C1 + perBuf;

    prep_kernel<<<108, 256, 0, stream>>>(primary_w, cls_w, obj_w, reg_w, pwW, clsW, regW);

    for (int b0 = 0; b0 < B; b0 += bc){
        tr_kernel<<<dim3(132, bc), 256, 0, stream>>>(f0, f1, f2, F, b0);
        pw_mfma<<<dim3(66, bc, 2), 256, 0, stream>>>(F, F, C0, R0, pwW, bn1_s, bn1_b, 0);
        dw_kernel<<<dim3(33, bc, 2), 384, 0, stream>>>(C0, R0, cheap_w, bn2_s, bn2_b, 0);
        pw_mfma<<<dim3(66, bc, 2), 256, 0, stream>>>(C0, R0, C1, R1, pwW, bn1_s, bn1_b, 1);
        dw_kernel<<<dim3(33, bc, 2), 384, 0, stream>>>(C1, R1, cheap_w, bn2_s, bn2_b, 1);
        head_cls_mfma<<<dim3(66, bc), 256, 0, stream>>>(C1, clsW, cls_b, obj_b, scores, b0);
        head_reg_mfma<<<dim3(66, bc), 256, 0, stream>>>(R1, regW, reg_b, boxes, b0);
    }
}

// Round 6
// 156.863 us; speedup vs baseline: 5.7972x; 1.0594x over previous
//
#include <hip/hip_runtime.h>
#include <math.h>

typedef unsigned short ushort_t;
typedef __attribute__((ext_vector_type(8))) short bf16x8;
typedef __attribute__((ext_vector_type(4))) float f32x4;

__device__ __forceinline__ float relu6f(float x){ return fminf(fmaxf(x,0.f),6.f); }
__device__ __forceinline__ float sigmoidf(float x){ return 1.f/(1.f+__expf(-x)); }
__device__ __forceinline__ float bf2f(unsigned u){ union{unsigned i; float f;}v; v.i=u<<16; return v.f; }
__device__ __forceinline__ unsigned f2bf(float f){ union{float f; unsigned i;}v; v.f=f;
    unsigned r = v.i + 0x7fff + ((v.i>>16)&1); return r>>16; }
__device__ __forceinline__ bf16x8 ldb8(const ushort_t* p){ return *reinterpret_cast<const bf16x8*>(p); }
#define MFMA(a,b,c) __builtin_amdgcn_mfma_f32_16x16x32_bf16((a),(b),(c),0,0,0)

// ---------------------------------------------------------------------------
// Weight prep (runs once): fp32 -> bf16.
// pwW [4][48][96]; clsW [3][96][96] (row 80 = obj, 81..95 = 0); regW [3][32][96]
// ---------------------------------------------------------------------------
__global__ __launch_bounds__(256) void prep_kernel(
    const float* __restrict__ primary_w, const float* __restrict__ cls_w,
    const float* __restrict__ obj_w, const float* __restrict__ reg_w,
    ushort_t* __restrict__ pwW, ushort_t* __restrict__ clsW, ushort_t* __restrict__ regW)
{
    int i = blockIdx.x*256 + threadIdx.x;
    if (i < 18432) pwW[i] = (ushort_t)f2bf(primary_w[i]);
    if (i < 27648){
        int lev = i/9216, rem = i - lev*9216, row = rem/96, c = rem - row*96;
        float v = (row < 80) ? cls_w[(lev*80 + row)*96 + c]
                : (row == 80) ? obj_w[lev*96 + c] : 0.f;
        clsW[i] = (ushort_t)f2bf(v);
    }
    if (i < 9216) regW[i] = (ushort_t)f2bf(reg_w[i]);
}

// ---------------------------------------------------------------------------
// Layer-0: fused transpose (CHW fp32 -> LDS bf16, swizzled) + pointwise MFMA
// for BOTH branches. grid (67, bc), block 256 (4 waves).
// Block tile = 128 anchors of one level. LDS xs[a][16 chunks of 8ch],
// chunk swizzle: ch_chunk ^ (a&7) ^ ((a>>3)&7)  -> conflict-free b128 reads.
// ---------------------------------------------------------------------------
__global__ __launch_bounds__(256) void pw0_kernel(
    const float* __restrict__ f0, const float* __restrict__ f1, const float* __restrict__ f2,
    ushort_t* __restrict__ Oc, ushort_t* __restrict__ Or,
    const ushort_t* __restrict__ pwW,
    const float* __restrict__ bn1_s, const float* __restrict__ bn1_b, int b0)
{
    __shared__ __align__(16) ushort_t xs[128*128];   // 32 KiB
    int bx = blockIdx.x, by = blockIdx.y;
    int lev, pb, HW, aoff;
    if (bx < 50){ lev=0; pb = bx*128;      HW=6400; aoff=0;    }
    else if (bx < 63){ lev=1; pb = (bx-50)*128; HW=1600; aoff=6400; }
    else { lev=2; pb = (bx-63)*128; HW=400;  aoff=8000; }
    const float* f = ((lev==0)? f0 : (lev==1)? f1 : f2) + (size_t)(b0+by)*96*HW;

    int tid = threadIdx.x;
    // ---- stage 128 anchors x 96 ch, fp32 -> bf16, transposed+swizzled ----
    #pragma unroll
    for (int k=0;k<12;k++){
        int idx = k*256 + tid;
        int q = idx & 31, c = idx >> 5;          // anchor-quad, channel
        int a0 = q*4;
        float4 v = make_float4(0.f,0.f,0.f,0.f);
        if (pb + a0 < HW) v = *reinterpret_cast<const float4*>(f + (size_t)c*HW + pb + a0);
        #pragma unroll
        for (int j=0;j<4;j++){
            int a = a0 + j;
            float val = (j==0)?v.x:(j==1)?v.y:(j==2)?v.z:v.w;
            int chunk = (c>>3) ^ (a&7) ^ ((a>>3)&7);
            xs[a*128 + chunk*8 + (c&7)] = (ushort_t)f2bf(val);
        }
    }
    __syncthreads();

    int lane = tid & 63, wv = tid >> 6;
    int l15 = lane & 15, rg = lane >> 4;

    // A fragments + BN for both branches (layer 0: pl = br*2)
    bf16x8 A[2][3][3];
    float sv[2][3][4], bv[2][3][4];
    #pragma unroll
    for (int br=0;br<2;br++){
        int pl = br*2;
        #pragma unroll
        for (int ot=0; ot<3; ot++){
            #pragma unroll
            for (int kt=0; kt<3; kt++)
                A[br][ot][kt] = ldb8(pwW + (size_t)(pl*48 + ot*16 + l15)*96 + kt*32 + rg*8);
            #pragma unroll
            for (int j=0;j<4;j++){
                int ch = ot*16 + rg*4 + j;
                sv[br][ot][j] = bn1_s[pl*48 + ch];
                bv[br][ot][j] = bn1_b[pl*48 + ch];
            }
        }
    }

    #pragma unroll
    for (int i=0;i<2;i++){
        int tl = wv + i*4;                 // local tile 0..7
        int p0 = pb + tl*16;
        if (p0 >= HW) continue;            // tile beyond this level
        int a_l = tl*16 + l15;             // local anchor
        int sw = (a_l&7) ^ ((a_l>>3)&7);
        bf16x8 Bf[3];
        #pragma unroll
        for (int kt=0;kt<3;kt++){
            int chunk = (kt*4 + rg) ^ sw;
            Bf[kt] = ldb8(xs + a_l*128 + chunk*8);
        }
        #pragma unroll
        for (int br=0;br<2;br++){
            f32x4 acc[3];
            #pragma unroll
            for (int ot=0;ot<3;ot++){ acc[ot][0]=0.f; acc[ot][1]=0.f; acc[ot][2]=0.f; acc[ot][3]=0.f; }
            #pragma unroll
            for (int kt=0;kt<3;kt++)
                #pragma unroll
                for (int ot=0;ot<3;ot++)
                    acc[ot] = MFMA(A[br][ot][kt], Bf[kt], acc[ot]);
            ushort_t* orow = (br ? Or : Oc) + ((size_t)by*8400 + aoff + p0 + l15)*96;
            #pragma unroll
            for (int ot=0;ot<3;ot++){
                uint2 u;
                u.x = f2bf(relu6f(fmaf(acc[ot][0], sv[br][ot][0], bv[br][ot][0])))
                   | (f2bf(relu6f(fmaf(acc[ot][1], sv[br][ot][1], bv[br][ot][1]))) << 16);
                u.y = f2bf(relu6f(fmaf(acc[ot][2], sv[br][ot][2], bv[br][ot][2])))
                   | (f2bf(relu6f(fmaf(acc[ot][3], sv[br][ot][3], bv[br][ot][3]))) << 16);
                *reinterpret_cast<uint2*>(orow + ot*16 + rg*4) = u;
            }
        }
    }
}

// ---------------------------------------------------------------------------
// Layer-1 pointwise 96->48 + BN + ReLU6 via MFMA, both branches (bf16 input).
// grid (66, bc, 2), block 256 (4 waves); wave = 2 anchor-tiles of 16.
// ---------------------------------------------------------------------------
__global__ __launch_bounds__(256) void pw1_kernel(
    const ushort_t* __restrict__ Xc, const ushort_t* __restrict__ Xr,
    ushort_t* __restrict__ Oc, ushort_t* __restrict__ Or,
    const ushort_t* __restrict__ pwW,
    const float* __restrict__ bn1_s, const float* __restrict__ bn1_b)
{
    int br = blockIdx.z, pl = br*2 + 1;
    const ushort_t* W = pwW + (size_t)pl*48*96;
    int lane = threadIdx.x & 63, wv = threadIdx.x >> 6;
    int l15 = lane & 15, rg = lane >> 4;

    bf16x8 A[3][3];
    #pragma unroll
    for (int ot=0; ot<3; ot++)
        #pragma unroll
        for (int kt=0; kt<3; kt++)
            A[ot][kt] = ldb8(W + (size_t)(ot*16 + l15)*96 + kt*32 + rg*8);

    float sv[3][4], bv[3][4];
    #pragma unroll
    for (int ot=0; ot<3; ot++)
        #pragma unroll
        for (int j=0;j<4;j++){
            int ch = ot*16 + rg*4 + j;
            sv[ot][j] = bn1_s[pl*48 + ch];
            bv[ot][j] = bn1_b[pl*48 + ch];
        }

    const ushort_t* X = (br ? Xr : Xc) + (size_t)blockIdx.y*8400*96;
    ushort_t* O = (br ? Or : Oc) + (size_t)blockIdx.y*8400*96;
    int wg = blockIdx.x*4 + wv;

    #pragma unroll
    for (int i=0;i<2;i++){
        int t = wg*2 + i;
        if (t >= 525) break;
        int a0 = t*16;
        bf16x8 Bf[3];
        #pragma unroll
        for (int kt=0;kt<3;kt++)
            Bf[kt] = ldb8(X + (size_t)(a0 + l15)*96 + kt*32 + rg*8);
        f32x4 acc[3];
        #pragma unroll
        for (int ot=0;ot<3;ot++){ acc[ot][0]=0.f; acc[ot][1]=0.f; acc[ot][2]=0.f; acc[ot][3]=0.f; }
        #pragma unroll
        for (int kt=0;kt<3;kt++)
            #pragma unroll
            for (int ot=0;ot<3;ot++)
                acc[ot] = MFMA(A[ot][kt], Bf[kt], acc[ot]);
        ushort_t* orow = O + (size_t)(a0 + l15)*96;
        #pragma unroll
        for (int ot=0;ot<3;ot++){
            uint2 u;
            u.x = f2bf(relu6f(fmaf(acc[ot][0], sv[ot][0], bv[ot][0])))
               | (f2bf(relu6f(fmaf(acc[ot][1], sv[ot][1], bv[ot][1]))) << 16);
            u.y = f2bf(relu6f(fmaf(acc[ot][2], sv[ot][2], bv[ot][2])))
               | (f2bf(relu6f(fmaf(acc[ot][3], sv[ot][3], bv[ot][3]))) << 16);
            *reinterpret_cast<uint2*>(orow + ot*16 + rg*4) = u;
        }
    }
}

// ---------------------------------------------------------------------------
// Depthwise 3x3 + BN + ReLU6, [a][96] layout. Reads ch[0,48), writes [48,96).
// grid (33, bc, 2), block 384 = 6 waves. Thread = 8-ch slice (wave-uniform)
// x 4 consecutive anchors. BRANCH-FREE predicated loads (address select +
// cndmask zero) so all 18 uint4 loads pipeline.
// ---------------------------------------------------------------------------
__global__ __launch_bounds__(384) void dw_kernel(
    ushort_t* __restrict__ Bc, ushort_t* __restrict__ Br,
    const float* __restrict__ cheap_w,
    const float* __restrict__ bn2_s, const float* __restrict__ bn2_b, int li)
{
    int br = blockIdx.z, pl = br*2 + li;
    int s8 = __builtin_amdgcn_readfirstlane(((int)threadIdx.x >> 6) * 8);

    int qa = blockIdx.x*64 + ((int)threadIdx.x & 63);
    int a0 = qa*4;
    if (a0 >= 8400) return;
    int lev, W, aoff;
    if (a0 < 6400){ lev=0; W=80; aoff=0; }
    else if (a0 < 8000){ lev=1; W=40; aoff=6400; }
    else { lev=2; W=20; aoff=8000; }
    int p = a0 - aoff;
    int h = (lev==0) ? p/80 : (lev==1) ? p/40 : p/20;
    int x0 = p - h*W;                 // multiple of 4; anchors a0..a0+3 same row

    ushort_t* base = (br ? Br : Bc) + ((size_t)blockIdx.y*8400 + a0)*96 + s8;

    float acc[4][8];
    #pragma unroll
    for (int j=0;j<4;j++)
        #pragma unroll
        for (int c=0;c<8;c++) acc[j][c] = 0.f;

    #pragma unroll
    for (int dy=-1; dy<=1; dy++){
        int hh = h + dy;
        bool rv = (unsigned)hh < (unsigned)W;    // H == W (square levels)
        float xv[6][8];
        #pragma unroll
        for (int i=0;i<6;i++){
            int px = x0 + i - 1;
            bool v = rv && ((unsigned)px < (unsigned)W);
            ptrdiff_t off = v ? (ptrdiff_t)(dy*W + i - 1)*96 : 0;   // address select
            uint4 u = *reinterpret_cast<const uint4*>(base + off);  // unconditional
            u.x = v ? u.x : 0u; u.y = v ? u.y : 0u;
            u.z = v ? u.z : 0u; u.w = v ? u.w : 0u;
            xv[i][0]=bf2f(u.x&0xffffu); xv[i][1]=bf2f(u.x>>16);
            xv[i][2]=bf2f(u.y&0xffffu); xv[i][3]=bf2f(u.y>>16);
            xv[i][4]=bf2f(u.z&0xffffu); xv[i][5]=bf2f(u.z>>16);
            xv[i][6]=bf2f(u.w&0xffffu); xv[i][7]=bf2f(u.w>>16);
        }
        #pragma unroll
        for (int c=0;c<8;c++){
            // wave-uniform indices -> scalar loads (SGPR operands in the FMAs)
            float w0 = cheap_w[(pl*48 + s8 + c)*9 + (dy+1)*3 + 0];
            float w1 = cheap_w[(pl*48 + s8 + c)*9 + (dy+1)*3 + 1];
            float w2 = cheap_w[(pl*48 + s8 + c)*9 + (dy+1)*3 + 2];
            #pragma unroll
            for (int j=0;j<4;j++)
                acc[j][c] = fmaf(xv[j][c], w0,
                            fmaf(xv[j+1][c], w1,
                            fmaf(xv[j+2][c], w2, acc[j][c])));
        }
    }

    float s2v[8], b2v[8];
    #pragma unroll
    for (int c=0;c<8;c++){
        s2v[c] = bn2_s[pl*48 + s8 + c];
        b2v[c] = bn2_b[pl*48 + s8 + c];
    }
    #pragma unroll
    for (int j=0;j<4;j++){
        uint4 o;
        o.x = f2bf(relu6f(fmaf(acc[j][0], s2v[0], b2v[0])))
           | (f2bf(relu6f(fmaf(acc[j][1], s2v[1], b2v[1]))) << 16);
        o.y = f2bf(relu6f(fmaf(acc[j][2], s2v[2], b2v[2])))
           | (f2bf(relu6f(fmaf(acc[j][3], s2v[3], b2v[3]))) << 16);
        o.z = f2bf(relu6f(fmaf(acc[j][4], s2v[4], b2v[4])))
           | (f2bf(relu6f(fmaf(acc[j][5], s2v[5], b2v[5]))) << 16);
        o.w = f2bf(relu6f(fmaf(acc[j][6], s2v[6], b2v[6])))
           | (f2bf(relu6f(fmaf(acc[j][7], s2v[7], b2v[7]))) << 16);
        *reinterpret_cast<uint4*>(base + j*96 + 48) = o;
    }
}

// ---------------------------------------------------------------------------
// Head cls+obj via MFMA. N = 96 (80 cls + obj@80 + pad). grid (66, bc).
// ---------------------------------------------------------------------------
__global__ __launch_bounds__(256) void head_cls_mfma(
    const ushort_t* __restrict__ Xc, const ushort_t* __restrict__ clsW,
    const float* __restrict__ cls_b_all, const float* __restrict__ obj_b_all,
    float* __restrict__ scores, int b0)
{
    int lane = threadIdx.x & 63, wv = threadIdx.x >> 6;
    int l15 = lane & 15, rg = lane >> 4;
    const ushort_t* X = Xc + (size_t)blockIdx.y*8400*96;
    float* sbase = scores + (size_t)(b0 + blockIdx.y)*8400*80;
    int wg = blockIdx.x*4 + wv;

    bf16x8 A[6][3];
    float cb[5][4];
    float obv = 0.f;
    int curlev = -1;

    for (int i=0;i<2;i++){
        int t = wg*2 + i;
        if (t >= 525) break;
        int lev = (t < 400) ? 0 : (t < 500) ? 1 : 2;
        if (lev != curlev){
            curlev = lev;
            const ushort_t* Wl = clsW + (size_t)lev*96*96;
            #pragma unroll
            for (int ot=0; ot<6; ot++)
                #pragma unroll
                for (int kt=0; kt<3; kt++)
                    A[ot][kt] = ldb8(Wl + (size_t)(ot*16 + l15)*96 + kt*32 + rg*8);
            #pragma unroll
            for (int ot=0; ot<5; ot++)
                #pragma unroll
                for (int j=0;j<4;j++)
                    cb[ot][j] = cls_b_all[lev*80 + ot*16 + rg*4 + j];
            obv = obj_b_all[lev];
        }
        int a0 = t*16;
        bf16x8 Bf[3];
        #pragma unroll
        for (int kt=0;kt<3;kt++)
            Bf[kt] = ldb8(X + (size_t)(a0 + l15)*96 + kt*32 + rg*8);
        f32x4 acc[6];
        #pragma unroll
        for (int ot=0;ot<6;ot++){ acc[ot][0]=0.f; acc[ot][1]=0.f; acc[ot][2]=0.f; acc[ot][3]=0.f; }
        #pragma unroll
        for (int kt=0;kt<3;kt++)
            #pragma unroll
            for (int ot=0;ot<6;ot++)
                acc[ot] = MFMA(A[ot][kt], Bf[kt], acc[ot]);

        float objp = acc[5][0];                  // row 80 lives in rg==0 lanes
        float objv = __shfl(objp, l15) + obv;    // broadcast to all rgs of this anchor
        float* srow = sbase + (size_t)(a0 + l15)*80;
        #pragma unroll
        for (int ot=0;ot<5;ot++){
            f32x4 o;
            #pragma unroll
            for (int j=0;j<4;j++)
                o[j] = sigmoidf(acc[ot][j] + cb[ot][j] + objv);
            *reinterpret_cast<f32x4*>(srow + ot*16 + rg*4) = o;
        }
    }
}

// ---------------------------------------------------------------------------
// Head reg via MFMA + in-register DFL + boxes. grid (66, bc).
// ---------------------------------------------------------------------------
__global__ __launch_bounds__(256) void head_reg_mfma(
    const ushort_t* __restrict__ Xr, const ushort_t* __restrict__ regW,
    const float* __restrict__ reg_b_all, float* __restrict__ boxes, int b0)
{
    int lane = threadIdx.x & 63, wv = threadIdx.x >> 6;
    int l15 = lane & 15, rg = lane >> 4;
    const ushort_t* X = Xr + (size_t)blockIdx.y*8400*96;
    float* bbase = boxes + (size_t)(b0 + blockIdx.y)*8400*4;
    int wg = blockIdx.x*4 + wv;

    bf16x8 A[2][3];
    float rb[2][4];
    float sc = 8.f; int aoff = 0, Wd = 80, curlev = -1;

    for (int i=0;i<2;i++){
        int t = wg*2 + i;
        if (t >= 525) break;
        int lev = (t < 400) ? 0 : (t < 500) ? 1 : 2;
        if (lev != curlev){
            curlev = lev;
            const ushort_t* Wl = regW + (size_t)lev*32*96;
            #pragma unroll
            for (int ot=0; ot<2; ot++)
                #pragma unroll
                for (int kt=0; kt<3; kt++)
                    A[ot][kt] = ldb8(Wl + (size_t)(ot*16 + l15)*96 + kt*32 + rg*8);
            #pragma unroll
            for (int ot=0; ot<2; ot++)
                #pragma unroll
                for (int j=0;j<4;j++)
                    rb[ot][j] = reg_b_all[lev*32 + ot*16 + rg*4 + j];
            sc   = (lev==0) ? 8.f : (lev==1) ? 16.f : 32.f;
            aoff = (lev==0) ? 0   : (lev==1) ? 6400 : 8000;
            Wd   = (lev==0) ? 80  : (lev==1) ? 40   : 20;
        }
        int a0 = t*16;
        bf16x8 Bf[3];
        #pragma unroll
        for (int kt=0;kt<3;kt++)
            Bf[kt] = ldb8(X + (size_t)(a0 + l15)*96 + kt*32 + rg*8);
        f32x4 acc[2];
        #pragma unroll
        for (int ot=0;ot<2;ot++){ acc[ot][0]=0.f; acc[ot][1]=0.f; acc[ot][2]=0.f; acc[ot][3]=0.f; }
        #pragma unroll
        for (int kt=0;kt<3;kt++)
            #pragma unroll
            for (int ot=0;ot<2;ot++)
                acc[ot] = MFMA(A[ot][kt], Bf[kt], acc[ot]);

        // DFL softmax-expectation, 8-bin groups split across rg-pairs
        float rbase = (float)((rg & 1) * 4);
        float lv[2];
        #pragma unroll
        for (int ot=0;ot<2;ot++){
            float tv[4];
            #pragma unroll
            for (int j=0;j<4;j++) tv[j] = acc[ot][j] + rb[ot][j];
            float m = fmaxf(fmaxf(tv[0],tv[1]), fmaxf(tv[2],tv[3]));
            m = fmaxf(m, __shfl_xor(m, 16));
            float se = 0.f, ne = 0.f;
            #pragma unroll
            for (int j=0;j<4;j++){
                float e = __expf(tv[j] - m);
                se += e; ne = fmaf(e, rbase + (float)j, ne);
            }
            float den = se + __shfl_xor(se, 16);
            float num = ne + __shfl_xor(ne, 16);
            lv[ot] = num / den * sc;
        }
        int a_img = a0 + l15;
        int p = a_img - aoff;
        int hh = (curlev==0) ? p/80 : (curlev==1) ? p/40 : p/20;
        int xx = p - hh*Wd;
        float ax = (xx + 0.5f)*sc, ay = (hh + 0.5f)*sc;
        float v0 = ax - lv[0];
        float v1 = ax + lv[1];
        float w0 = ay - lv[0];
        float w1 = ay + lv[1];
        float y1g = __shfl_xor(w0, 32);
        float y2g = __shfl_xor(w1, 32);
        if (lane < 16){
            f32x4 o; o[0] = v0; o[1] = y1g; o[2] = v1; o[3] = y2g;
            *reinterpret_cast<f32x4*>(bbase + (size_t)a_img*4) = o;
        }
    }
}

// ---------------------------------------------------------------------------
extern "C" void kernel_launch(void* const* d_in, const int* in_sizes, int n_in,
                              void* d_out, int out_size, void* d_ws, size_t ws_size,
                              hipStream_t stream)
{
    const float* f0        = (const float*)d_in[0];
    const float* f1        = (const float*)d_in[1];
    const float* f2        = (const float*)d_in[2];
    const float* primary_w = (const float*)d_in[3];
    const float* bn1_s     = (const float*)d_in[4];
    const float* bn1_b     = (const float*)d_in[5];
    const float* cheap_w   = (const float*)d_in[6];
    const float* bn2_s     = (const float*)d_in[7];
    const float* bn2_b     = (const float*)d_in[8];
    const float* cls_w     = (const float*)d_in[9];
    const float* cls_b     = (const float*)d_in[10];
    const float* obj_w     = (const float*)d_in[11];
    const float* obj_b     = (const float*)d_in[12];
    const float* reg_w     = (const float*)d_in[13];
    const float* reg_b     = (const float*)d_in[14];

    const int B = 16;
    float* boxes  = (float*)d_out;
    float* scores = boxes + (size_t)16*8400*4;

    ushort_t* pwW  = (ushort_t*)d_ws;
    ushort_t* clsW = pwW + 18432;
    ushort_t* regW = clsW + 27648;
    ushort_t* bufs = regW + 9216;
    size_t used0 = (size_t)55296*2;

    int bc = 16;
    while (bc > 1 && used0 + 4*(size_t)bc*8400*96*2 > ws_size) bc >>= 1;
    size_t perBuf = (size_t)bc*8400*96;
    ushort_t* C0 = bufs;
    ushort_t* R0 = C0 + perBuf;
    ushort_t* C1 = R0 + perBuf;
    ushort_t* R1 = C1 + perBuf;

    prep_kernel<<<108, 256, 0, stream>>>(primary_w, cls_w, obj_w, reg_w, pwW, clsW, regW);

    for (int b0 = 0; b0 < B; b0 += bc){
        pw0_kernel<<<dim3(67, bc), 256, 0, stream>>>(
            f0, f1, f2, C0, R0, pwW, bn1_s, bn1_b, b0);
        dw_kernel<<<dim3(33, bc, 2), 384, 0, stream>>>(C0, R0, cheap_w, bn2_s, bn2_b, 0);
        pw1_kernel<<<dim3(66, bc, 2), 256, 0, stream>>>(
            C0, R0, C1, R1, pwW, bn1_s, bn1_b);
        dw_kernel<<<dim3(33, bc, 2), 384, 0, stream>>>(C1, R1, cheap_w, bn2_s, bn2_b, 1);
        head_cls_mfma<<<dim3(66, bc), 256, 0, stream>>>(
            C1, clsW, cls_b, obj_b, scores, b0);
        head_reg_mfma<<<dim3(66, bc), 256, 0, stream>>>(
            R1, regW, reg_b, boxes, b0);
    }
}

// Round 7
// 113.291 us; speedup vs baseline: 8.0267x; 1.3846x over previous
//
#include <hip/hip_runtime.h>
#include <math.h>

typedef unsigned short ushort_t;
typedef __attribute__((ext_vector_type(8))) short bf16x8;
typedef __attribute__((ext_vector_type(4))) float f32x4;

#define CHK 67200            // chunk plane stride in ushorts (8400 anchors * 8 ch)
#define IMG 806400           // per-image buffer (12 chunks * CHK)

__device__ __forceinline__ float relu6f(float x){ return fminf(fmaxf(x,0.f),6.f); }
__device__ __forceinline__ float sigmoidf(float x){ return 1.f/(1.f+__expf(-x)); }
__device__ __forceinline__ float bf2f(unsigned u){ union{unsigned i; float f;}v; v.i=u<<16; return v.f; }
__device__ __forceinline__ unsigned f2bf(float f){ union{float f; unsigned i;}v; v.f=f;
    unsigned r = v.i + 0x7fff + ((v.i>>16)&1); return r>>16; }
__device__ __forceinline__ bf16x8 ldb8(const ushort_t* p){ return *reinterpret_cast<const bf16x8*>(p); }
#define MFMA(a,b,c) __builtin_amdgcn_mfma_f32_16x16x32_bf16((a),(b),(c),0,0,0)

// ---------------------------------------------------------------------------
// Weight prep (runs once): fp32 -> bf16.
// pwW [4][48][96]; clsW [3][96][96] (row 80 = obj, 81..95 = 0); regW [3][32][96]
// ---------------------------------------------------------------------------
__global__ __launch_bounds__(256) void prep_kernel(
    const float* __restrict__ primary_w, const float* __restrict__ cls_w,
    const float* __restrict__ obj_w, const float* __restrict__ reg_w,
    ushort_t* __restrict__ pwW, ushort_t* __restrict__ clsW, ushort_t* __restrict__ regW)
{
    int i = blockIdx.x*256 + threadIdx.x;
    if (i < 18432) pwW[i] = (ushort_t)f2bf(primary_w[i]);
    if (i < 27648){
        int lev = i/9216, rem = i - lev*9216, row = rem/96, c = rem - row*96;
        float v = (row < 80) ? cls_w[(lev*80 + row)*96 + c]
                : (row == 80) ? obj_w[lev*96 + c] : 0.f;
        clsW[i] = (ushort_t)f2bf(v);
    }
    if (i < 9216) regW[i] = (ushort_t)f2bf(reg_w[i]);
}

// ---------------------------------------------------------------------------
// Layer-0: fused transpose (CHW fp32 -> LDS bf16, swizzled) + pointwise MFMA
// for BOTH branches. grid (67, bc), block 256 (4 waves).
// Output: chunk-major [12][8400][8] bf16 (chunks 0..5 = primary 48ch).
// ---------------------------------------------------------------------------
__global__ __launch_bounds__(256) void pw0_kernel(
    const float* __restrict__ f0, const float* __restrict__ f1, const float* __restrict__ f2,
    ushort_t* __restrict__ Oc, ushort_t* __restrict__ Or,
    const ushort_t* __restrict__ pwW,
    const float* __restrict__ bn1_s, const float* __restrict__ bn1_b, int b0)
{
    __shared__ __align__(16) ushort_t xs[128*128];   // 32 KiB
    int bx = blockIdx.x, by = blockIdx.y;
    int lev, pb, HW, aoff;
    if (bx < 50){ lev=0; pb = bx*128;      HW=6400; aoff=0;    }
    else if (bx < 63){ lev=1; pb = (bx-50)*128; HW=1600; aoff=6400; }
    else { lev=2; pb = (bx-63)*128; HW=400;  aoff=8000; }
    const float* f = ((lev==0)? f0 : (lev==1)? f1 : f2) + (size_t)(b0+by)*96*HW;

    int tid = threadIdx.x;
    // ---- stage 128 anchors x 96 ch, fp32 -> bf16, transposed+swizzled ----
    #pragma unroll
    for (int k=0;k<12;k++){
        int idx = k*256 + tid;
        int q = idx & 31, c = idx >> 5;          // anchor-quad, channel
        int a0 = q*4;
        float4 v = make_float4(0.f,0.f,0.f,0.f);
        if (pb + a0 < HW) v = *reinterpret_cast<const float4*>(f + (size_t)c*HW + pb + a0);
        #pragma unroll
        for (int j=0;j<4;j++){
            int a = a0 + j;
            float val = (j==0)?v.x:(j==1)?v.y:(j==2)?v.z:v.w;
            int chunk = (c>>3) ^ (a&7) ^ ((a>>3)&7);
            xs[a*128 + chunk*8 + (c&7)] = (ushort_t)f2bf(val);
        }
    }
    __syncthreads();

    int lane = tid & 63, wv = tid >> 6;
    int l15 = lane & 15, rg = lane >> 4;

    // A fragments + BN for both branches (layer 0: pl = br*2)
    bf16x8 A[2][3][3];
    float sv[2][3][4], bv[2][3][4];
    #pragma unroll
    for (int br=0;br<2;br++){
        int pl = br*2;
        #pragma unroll
        for (int ot=0; ot<3; ot++){
            #pragma unroll
            for (int kt=0; kt<3; kt++)
                A[br][ot][kt] = ldb8(pwW + (size_t)(pl*48 + ot*16 + l15)*96 + kt*32 + rg*8);
            #pragma unroll
            for (int j=0;j<4;j++){
                int ch = ot*16 + rg*4 + j;
                sv[br][ot][j] = bn1_s[pl*48 + ch];
                bv[br][ot][j] = bn1_b[pl*48 + ch];
            }
        }
    }

    #pragma unroll
    for (int i=0;i<2;i++){
        int tl = wv + i*4;                 // local tile 0..7
        int p0 = pb + tl*16;
        if (p0 >= HW) continue;            // tile beyond this level
        int a_l = tl*16 + l15;             // local anchor
        int sw = (a_l&7) ^ ((a_l>>3)&7);
        bf16x8 Bf[3];
        #pragma unroll
        for (int kt=0;kt<3;kt++){
            int chunk = (kt*4 + rg) ^ sw;
            Bf[kt] = ldb8(xs + a_l*128 + chunk*8);
        }
        size_t A_g = (size_t)(aoff + p0 + l15);     // global anchor index
        #pragma unroll
        for (int br=0;br<2;br++){
            f32x4 acc[3];
            #pragma unroll
            for (int ot=0;ot<3;ot++){ acc[ot][0]=0.f; acc[ot][1]=0.f; acc[ot][2]=0.f; acc[ot][3]=0.f; }
            #pragma unroll
            for (int kt=0;kt<3;kt++)
                #pragma unroll
                for (int ot=0;ot<3;ot++)
                    acc[ot] = MFMA(A[br][ot][kt], Bf[kt], acc[ot]);
            ushort_t* obase = (br ? Or : Oc) + (size_t)by*IMG;
            #pragma unroll
            for (int ot=0;ot<3;ot++){
                uint2 u;
                u.x = f2bf(relu6f(fmaf(acc[ot][0], sv[br][ot][0], bv[br][ot][0])))
                   | (f2bf(relu6f(fmaf(acc[ot][1], sv[br][ot][1], bv[br][ot][1]))) << 16);
                u.y = f2bf(relu6f(fmaf(acc[ot][2], sv[br][ot][2], bv[br][ot][2])))
                   | (f2bf(relu6f(fmaf(acc[ot][3], sv[br][ot][3], bv[br][ot][3]))) << 16);
                int chunk = 2*ot + (rg>>1);
                *reinterpret_cast<uint2*>(obase + (size_t)chunk*CHK + A_g*8 + (rg&1)*4) = u;
            }
        }
    }
}

// ---------------------------------------------------------------------------
// Layer-1 pointwise 96->48 + BN + ReLU6 via MFMA, both branches.
// Chunk-major in/out. grid (66, bc, 2), block 256 (4 waves).
// ---------------------------------------------------------------------------
__global__ __launch_bounds__(256) void pw1_kernel(
    const ushort_t* __restrict__ Xc, const ushort_t* __restrict__ Xr,
    ushort_t* __restrict__ Oc, ushort_t* __restrict__ Or,
    const ushort_t* __restrict__ pwW,
    const float* __restrict__ bn1_s, const float* __restrict__ bn1_b)
{
    int br = blockIdx.z, pl = br*2 + 1;
    const ushort_t* W = pwW + (size_t)pl*48*96;
    int lane = threadIdx.x & 63, wv = threadIdx.x >> 6;
    int l15 = lane & 15, rg = lane >> 4;

    bf16x8 A[3][3];
    #pragma unroll
    for (int ot=0; ot<3; ot++)
        #pragma unroll
        for (int kt=0; kt<3; kt++)
            A[ot][kt] = ldb8(W + (size_t)(ot*16 + l15)*96 + kt*32 + rg*8);

    float sv[3][4], bv[3][4];
    #pragma unroll
    for (int ot=0; ot<3; ot++)
        #pragma unroll
        for (int j=0;j<4;j++){
            int ch = ot*16 + rg*4 + j;
            sv[ot][j] = bn1_s[pl*48 + ch];
            bv[ot][j] = bn1_b[pl*48 + ch];
        }

    const ushort_t* X = (br ? Xr : Xc) + (size_t)blockIdx.y*IMG;
    ushort_t* O = (br ? Or : Oc) + (size_t)blockIdx.y*IMG;
    int wg = blockIdx.x*4 + wv;

    #pragma unroll
    for (int i=0;i<2;i++){
        int t = wg*2 + i;
        if (t >= 525) break;
        size_t a = (size_t)(t*16 + l15);
        bf16x8 Bf[3];
        #pragma unroll
        for (int kt=0;kt<3;kt++)
            Bf[kt] = ldb8(X + (size_t)(kt*4 + rg)*CHK + a*8);
        f32x4 acc[3];
        #pragma unroll
        for (int ot=0;ot<3;ot++){ acc[ot][0]=0.f; acc[ot][1]=0.f; acc[ot][2]=0.f; acc[ot][3]=0.f; }
        #pragma unroll
        for (int kt=0;kt<3;kt++)
            #pragma unroll
            for (int ot=0;ot<3;ot++)
                acc[ot] = MFMA(A[ot][kt], Bf[kt], acc[ot]);
        #pragma unroll
        for (int ot=0;ot<3;ot++){
            uint2 u;
            u.x = f2bf(relu6f(fmaf(acc[ot][0], sv[ot][0], bv[ot][0])))
               | (f2bf(relu6f(fmaf(acc[ot][1], sv[ot][1], bv[ot][1]))) << 16);
            u.y = f2bf(relu6f(fmaf(acc[ot][2], sv[ot][2], bv[ot][2])))
               | (f2bf(relu6f(fmaf(acc[ot][3], sv[ot][3], bv[ot][3]))) << 16);
            int chunk = 2*ot + (rg>>1);
            *reinterpret_cast<uint2*>(O + (size_t)chunk*CHK + a*8 + (rg&1)*4) = u;
        }
    }
}

// ---------------------------------------------------------------------------
// Depthwise 3x3 + BN + ReLU6, chunk-major. Reads chunks [0,6) (primary 48ch),
// writes chunks [6,12) (cheap 48ch). grid (33, bc, 2), block 384 = 6 waves;
// wave = chunk (uniform), thread = 4 consecutive anchors. All loads/stores
// are dense consecutive 16B (full line utilization). Branch-free predication.
// ---------------------------------------------------------------------------
__global__ __launch_bounds__(384) void dw_kernel(
    ushort_t* __restrict__ Bc, ushort_t* __restrict__ Br,
    const float* __restrict__ cheap_w,
    const float* __restrict__ bn2_s, const float* __restrict__ bn2_b, int li)
{
    int br = blockIdx.z, pl = br*2 + li;
    int ck = __builtin_amdgcn_readfirstlane((int)threadIdx.x >> 6);   // chunk 0..5
    int s8 = ck*8;

    int qa = blockIdx.x*64 + ((int)threadIdx.x & 63);
    int a0 = qa*4;
    if (a0 >= 8400) return;
    int lev, W, aoff;
    if (a0 < 6400){ lev=0; W=80; aoff=0; }
    else if (a0 < 8000){ lev=1; W=40; aoff=6400; }
    else { lev=2; W=20; aoff=8000; }
    int p = a0 - aoff;
    int h = (lev==0) ? p/80 : (lev==1) ? p/40 : p/20;
    int x0 = p - h*W;                 // multiple of 4; anchors a0..a0+3 same row

    ushort_t* bufbase = (br ? Br : Bc) + (size_t)blockIdx.y*IMG;
    const ushort_t* src = bufbase + (size_t)ck*CHK + (size_t)a0*8;
    ushort_t*       dst = bufbase + (size_t)(6+ck)*CHK + (size_t)a0*8;

    float acc[4][8];
    #pragma unroll
    for (int j=0;j<4;j++)
        #pragma unroll
        for (int c=0;c<8;c++) acc[j][c] = 0.f;

    #pragma unroll
    for (int dy=-1; dy<=1; dy++){
        int hh = h + dy;
        bool rv = (unsigned)hh < (unsigned)W;    // H == W (square levels)
        float xv[6][8];
        #pragma unroll
        for (int i=0;i<6;i++){
            int px = x0 + i - 1;
            bool v = rv && ((unsigned)px < (unsigned)W);
            ptrdiff_t off = v ? (ptrdiff_t)(dy*W + i - 1)*8 : 0;    // address select
            uint4 u = *reinterpret_cast<const uint4*>(src + off);   // unconditional
            u.x = v ? u.x : 0u; u.y = v ? u.y : 0u;
            u.z = v ? u.z : 0u; u.w = v ? u.w : 0u;
            xv[i][0]=bf2f(u.x&0xffffu); xv[i][1]=bf2f(u.x>>16);
            xv[i][2]=bf2f(u.y&0xffffu); xv[i][3]=bf2f(u.y>>16);
            xv[i][4]=bf2f(u.z&0xffffu); xv[i][5]=bf2f(u.z>>16);
            xv[i][6]=bf2f(u.w&0xffffu); xv[i][7]=bf2f(u.w>>16);
        }
        #pragma unroll
        for (int c=0;c<8;c++){
            // wave-uniform indices -> scalar loads (SGPR operands in the FMAs)
            float w0 = cheap_w[(pl*48 + s8 + c)*9 + (dy+1)*3 + 0];
            float w1 = cheap_w[(pl*48 + s8 + c)*9 + (dy+1)*3 + 1];
            float w2 = cheap_w[(pl*48 + s8 + c)*9 + (dy+1)*3 + 2];
            #pragma unroll
            for (int j=0;j<4;j++)
                acc[j][c] = fmaf(xv[j][c], w0,
                            fmaf(xv[j+1][c], w1,
                            fmaf(xv[j+2][c], w2, acc[j][c])));
        }
    }

    float s2v[8], b2v[8];
    #pragma unroll
    for (int c=0;c<8;c++){
        s2v[c] = bn2_s[pl*48 + s8 + c];
        b2v[c] = bn2_b[pl*48 + s8 + c];
    }
    #pragma unroll
    for (int j=0;j<4;j++){
        uint4 o;
        o.x = f2bf(relu6f(fmaf(acc[j][0], s2v[0], b2v[0])))
           | (f2bf(relu6f(fmaf(acc[j][1], s2v[1], b2v[1]))) << 16);
        o.y = f2bf(relu6f(fmaf(acc[j][2], s2v[2], b2v[2])))
           | (f2bf(relu6f(fmaf(acc[j][3], s2v[3], b2v[3]))) << 16);
        o.z = f2bf(relu6f(fmaf(acc[j][4], s2v[4], b2v[4])))
           | (f2bf(relu6f(fmaf(acc[j][5], s2v[5], b2v[5]))) << 16);
        o.w = f2bf(relu6f(fmaf(acc[j][6], s2v[6], b2v[6])))
           | (f2bf(relu6f(fmaf(acc[j][7], s2v[7], b2v[7]))) << 16);
        *reinterpret_cast<uint4*>(dst + j*8) = o;
    }
}

// ---------------------------------------------------------------------------
// Head cls+obj via MFMA. Chunk-major input. grid (66, bc).
// ---------------------------------------------------------------------------
__global__ __launch_bounds__(256) void head_cls_mfma(
    const ushort_t* __restrict__ Xc, const ushort_t* __restrict__ clsW,
    const float* __restrict__ cls_b_all, const float* __restrict__ obj_b_all,
    float* __restrict__ scores, int b0)
{
    int lane = threadIdx.x & 63, wv = threadIdx.x >> 6;
    int l15 = lane & 15, rg = lane >> 4;
    const ushort_t* X = Xc + (size_t)blockIdx.y*IMG;
    float* sbase = scores + (size_t)(b0 + blockIdx.y)*8400*80;
    int wg = blockIdx.x*4 + wv;

    bf16x8 A[6][3];
    float cb[5][4];
    float obv = 0.f;
    int curlev = -1;

    for (int i=0;i<2;i++){
        int t = wg*2 + i;
        if (t >= 525) break;
        int lev = (t < 400) ? 0 : (t < 500) ? 1 : 2;
        if (lev != curlev){
            curlev = lev;
            const ushort_t* Wl = clsW + (size_t)lev*96*96;
            #pragma unroll
            for (int ot=0; ot<6; ot++)
                #pragma unroll
                for (int kt=0; kt<3; kt++)
                    A[ot][kt] = ldb8(Wl + (size_t)(ot*16 + l15)*96 + kt*32 + rg*8);
            #pragma unroll
            for (int ot=0; ot<5; ot++)
                #pragma unroll
                for (int j=0;j<4;j++)
                    cb[ot][j] = cls_b_all[lev*80 + ot*16 + rg*4 + j];
            obv = obj_b_all[lev];
        }
        size_t a = (size_t)(t*16 + l15);
        bf16x8 Bf[3];
        #pragma unroll
        for (int kt=0;kt<3;kt++)
            Bf[kt] = ldb8(X + (size_t)(kt*4 + rg)*CHK + a*8);
        f32x4 acc[6];
        #pragma unroll
        for (int ot=0;ot<6;ot++){ acc[ot][0]=0.f; acc[ot][1]=0.f; acc[ot][2]=0.f; acc[ot][3]=0.f; }
        #pragma unroll
        for (int kt=0;kt<3;kt++)
            #pragma unroll
            for (int ot=0;ot<6;ot++)
                acc[ot] = MFMA(A[ot][kt], Bf[kt], acc[ot]);

        float objp = acc[5][0];                  // row 80 lives in rg==0 lanes
        float objv = __shfl(objp, l15) + obv;    // broadcast to all rgs of this anchor
        float* srow = sbase + a*80;
        #pragma unroll
        for (int ot=0;ot<5;ot++){
            f32x4 o;
            #pragma unroll
            for (int j=0;j<4;j++)
                o[j] = sigmoidf(acc[ot][j] + cb[ot][j] + objv);
            *reinterpret_cast<f32x4*>(srow + ot*16 + rg*4) = o;
        }
    }
}

// ---------------------------------------------------------------------------
// Head reg via MFMA + in-register DFL + boxes. Chunk-major input. grid (66, bc).
// ---------------------------------------------------------------------------
__global__ __launch_bounds__(256) void head_reg_mfma(
    const ushort_t* __restrict__ Xr, const ushort_t* __restrict__ regW,
    const float* __restrict__ reg_b_all, float* __restrict__ boxes, int b0)
{
    int lane = threadIdx.x & 63, wv = threadIdx.x >> 6;
    int l15 = lane & 15, rg = lane >> 4;
    const ushort_t* X = Xr + (size_t)blockIdx.y*IMG;
    float* bbase = boxes + (size_t)(b0 + blockIdx.y)*8400*4;
    int wg = blockIdx.x*4 + wv;

    bf16x8 A[2][3];
    float rb[2][4];
    float sc = 8.f; int aoff = 0, Wd = 80, curlev = -1;

    for (int i=0;i<2;i++){
        int t = wg*2 + i;
        if (t >= 525) break;
        int lev = (t < 400) ? 0 : (t < 500) ? 1 : 2;
        if (lev != curlev){
            curlev = lev;
            const ushort_t* Wl = regW + (size_t)lev*32*96;
            #pragma unroll
            for (int ot=0; ot<2; ot++)
                #pragma unroll
                for (int kt=0; kt<3; kt++)
                    A[ot][kt] = ldb8(Wl + (size_t)(ot*16 + l15)*96 + kt*32 + rg*8);
            #pragma unroll
            for (int ot=0; ot<2; ot++)
                #pragma unroll
                for (int j=0;j<4;j++)
                    rb[ot][j] = reg_b_all[lev*32 + ot*16 + rg*4 + j];
            sc   = (lev==0) ? 8.f : (lev==1) ? 16.f : 32.f;
            aoff = (lev==0) ? 0   : (lev==1) ? 6400 : 8000;
            Wd   = (lev==0) ? 80  : (lev==1) ? 40   : 20;
        }
        int a0 = t*16;
        bf16x8 Bf[3];
        #pragma unroll
        for (int kt=0;kt<3;kt++)
            Bf[kt] = ldb8(X + (size_t)(kt*4 + rg)*CHK + (size_t)(a0 + l15)*8);
        f32x4 acc[2];
        #pragma unroll
        for (int ot=0;ot<2;ot++){ acc[ot][0]=0.f; acc[ot][1]=0.f; acc[ot][2]=0.f; acc[ot][3]=0.f; }
        #pragma unroll
        for (int kt=0;kt<3;kt++)
            #pragma unroll
            for (int ot=0;ot<2;ot++)
                acc[ot] = MFMA(A[ot][kt], Bf[kt], acc[ot]);

        // DFL softmax-expectation, 8-bin groups split across rg-pairs
        float rbase = (float)((rg & 1) * 4);
        float lv[2];
        #pragma unroll
        for (int ot=0;ot<2;ot++){
            float tv[4];
            #pragma unroll
            for (int j=0;j<4;j++) tv[j] = acc[ot][j] + rb[ot][j];
            float m = fmaxf(fmaxf(tv[0],tv[1]), fmaxf(tv[2],tv[3]));
            m = fmaxf(m, __shfl_xor(m, 16));
            float se = 0.f, ne = 0.f;
            #pragma unroll
            for (int j=0;j<4;j++){
                float e = __expf(tv[j] - m);
                se += e; ne = fmaf(e, rbase + (float)j, ne);
            }
            float den = se + __shfl_xor(se, 16);
            float num = ne + __shfl_xor(ne, 16);
            lv[ot] = num / den * sc;
        }
        int a_img = a0 + l15;
        int p = a_img - aoff;
        int hh = (curlev==0) ? p/80 : (curlev==1) ? p/40 : p/20;
        int xx = p - hh*Wd;
        float ax = (xx + 0.5f)*sc, ay = (hh + 0.5f)*sc;
        float v0 = ax - lv[0];
        float v1 = ax + lv[1];
        float w0 = ay - lv[0];
        float w1 = ay + lv[1];
        float y1g = __shfl_xor(w0, 32);
        float y2g = __shfl_xor(w1, 32);
        if (lane < 16){
            f32x4 o; o[0] = v0; o[1] = y1g; o[2] = v1; o[3] = y2g;
            *reinterpret_cast<f32x4*>(bbase + (size_t)a_img*4) = o;
        }
    }
}

// ---------------------------------------------------------------------------
extern "C" void kernel_launch(void* const* d_in, const int* in_sizes, int n_in,
                              void* d_out, int out_size, void* d_ws, size_t ws_size,
                              hipStream_t stream)
{
    const float* f0        = (const float*)d_in[0];
    const float* f1        = (const float*)d_in[1];
    const float* f2        = (const float*)d_in[2];
    const float* primary_w = (const float*)d_in[3];
    const float* bn1_s     = (const float*)d_in[4];
    const float* bn1_b     = (const float*)d_in[5];
    const float* cheap_w   = (const float*)d_in[6];
    const float* bn2_s     = (const float*)d_in[7];
    const float* bn2_b     = (const float*)d_in[8];
    const float* cls_w     = (const float*)d_in[9];
    const float* cls_b     = (const float*)d_in[10];
    const float* obj_w     = (const float*)d_in[11];
    const float* obj_b     = (const float*)d_in[12];
    const float* reg_w     = (const float*)d_in[13];
    const float* reg_b     = (const float*)d_in[14];

    const int B = 16;
    float* boxes  = (float*)d_out;
    float* scores = boxes + (size_t)16*8400*4;

    ushort_t* pwW  = (ushort_t*)d_ws;
    ushort_t* clsW = pwW + 18432;
    ushort_t* regW = clsW + 27648;
    ushort_t* bufs = regW + 9216;
    size_t used0 = (size_t)55296*2;

    int bc = 16;
    while (bc > 1 && used0 + 4*(size_t)bc*IMG*2 > ws_size) bc >>= 1;
    size_t perBuf = (size_t)bc*IMG;
    ushort_t* C0 = bufs;
    ushort_t* R0 = C0 + perBuf;
    ushort_t* C1 = R0 + perBuf;
    ushort_t* R1 = C1 + perBuf;

    prep_kernel<<<108, 256, 0, stream>>>(primary_w, cls_w, obj_w, reg_w, pwW, clsW, regW);

    for (int b0 = 0; b0 < B; b0 += bc){
        pw0_kernel<<<dim3(67, bc), 256, 0, stream>>>(
            f0, f1, f2, C0, R0, pwW, bn1_s, bn1_b, b0);
        dw_kernel<<<dim3(33, bc, 2), 384, 0, stream>>>(C0, R0, cheap_w, bn2_s, bn2_b, 0);
        pw1_kernel<<<dim3(66, bc, 2), 256, 0, stream>>>(
            C0, R0, C1, R1, pwW, bn1_s, bn1_b);
        dw_kernel<<<dim3(33, bc, 2), 384, 0, stream>>>(C1, R1, cheap_w, bn2_s, bn2_b, 1);
        head_cls_mfma<<<dim3(66, bc), 256, 0, stream>>>(
            C1, clsW, cls_b, obj_b, scores, b0);
        head_reg_mfma<<<dim3(66, bc), 256, 0, stream>>>(
            R1, regW, reg_b, boxes, b0);
    }
}

// Round 8
// 111.356 us; speedup vs baseline: 8.1662x; 1.0174x over previous
//
#include <hip/hip_runtime.h>
#include <math.h>

typedef unsigned short ushort_t;
typedef __attribute__((ext_vector_type(8))) short bf16x8;
typedef __attribute__((ext_vector_type(4))) float f32x4;

#define CHK 67200            // chunk plane stride in ushorts (8400 anchors * 8 ch)
#define IMG 806400           // per-image buffer (12 chunks * CHK)

__device__ __forceinline__ float relu6f(float x){ return fminf(fmaxf(x,0.f),6.f); }
__device__ __forceinline__ float sigmoidf(float x){ return 1.f/(1.f+__expf(-x)); }
__device__ __forceinline__ float bf2f(unsigned u){ union{unsigned i; float f;}v; v.i=u<<16; return v.f; }
__device__ __forceinline__ unsigned f2bf(float f){ union{float f; unsigned i;}v; v.f=f;
    unsigned r = v.i + 0x7fff + ((v.i>>16)&1); return r>>16; }
__device__ __forceinline__ bf16x8 ldb8(const ushort_t* p){ return *reinterpret_cast<const bf16x8*>(p); }
#define MFMA(a,b,c) __builtin_amdgcn_mfma_f32_16x16x32_bf16((a),(b),(c),0,0,0)

// ---------------------------------------------------------------------------
// Weight prep (runs once): fp32 -> bf16.
// pwW [4][48][96]; clsW [3][96][96] (row 80 = obj, 81..95 = 0); regW [3][32][96]
// ---------------------------------------------------------------------------
__global__ __launch_bounds__(256) void prep_kernel(
    const float* __restrict__ primary_w, const float* __restrict__ cls_w,
    const float* __restrict__ obj_w, const float* __restrict__ reg_w,
    ushort_t* __restrict__ pwW, ushort_t* __restrict__ clsW, ushort_t* __restrict__ regW)
{
    int i = blockIdx.x*256 + threadIdx.x;
    if (i < 18432) pwW[i] = (ushort_t)f2bf(primary_w[i]);
    if (i < 27648){
        int lev = i/9216, rem = i - lev*9216, row = rem/96, c = rem - row*96;
        float v = (row < 80) ? cls_w[(lev*80 + row)*96 + c]
                : (row == 80) ? obj_w[lev*96 + c] : 0.f;
        clsW[i] = (ushort_t)f2bf(v);
    }
    if (i < 9216) regW[i] = (ushort_t)f2bf(reg_w[i]);
}

// ---------------------------------------------------------------------------
// Layer-0 pointwise via MFMA, LDS-FREE. Each lane gathers its 24 fp32
// channels directly from CHW (per-channel, 16 lanes = 64B dense segment),
// converts to bf16 in registers, runs both branches' MFMA.
// grid (66, bc), block 256 (4 waves); wave = 2 anchor-tiles of 16.
// Output: chunk-major [12][8400][8] bf16 (chunks 0..5 = primary 48ch).
// ---------------------------------------------------------------------------
__global__ __launch_bounds__(256) void pw0_kernel(
    const float* __restrict__ f0, const float* __restrict__ f1, const float* __restrict__ f2,
    ushort_t* __restrict__ Oc, ushort_t* __restrict__ Or,
    const ushort_t* __restrict__ pwW,
    const float* __restrict__ bn1_s, const float* __restrict__ bn1_b, int b0)
{
    int lane = threadIdx.x & 63, wv = threadIdx.x >> 6;
    int l15 = lane & 15, rg = lane >> 4;
    int wg = blockIdx.x*4 + wv;
    int by = blockIdx.y;

    // A fragments for both branches (layer 0: pl = br*2)
    bf16x8 A[2][3][3];
    #pragma unroll
    for (int br=0;br<2;br++)
        #pragma unroll
        for (int ot=0; ot<3; ot++)
            #pragma unroll
            for (int kt=0; kt<3; kt++)
                A[br][ot][kt] = ldb8(pwW + (size_t)(br*96 + ot*16 + l15)*96 + kt*32 + rg*8);

    #pragma unroll
    for (int i=0;i<2;i++){
        int t = wg*2 + i;
        if (t >= 525) break;
        int lev  = (t < 400) ? 0 : (t < 500) ? 1 : 2;
        int HW   = (lev==0) ? 6400 : (lev==1) ? 1600 : 400;
        int tb   = (lev==0) ? 0    : (lev==1) ? 400  : 500;
        int aoff = (lev==0) ? 0    : (lev==1) ? 6400 : 8000;
        int p0   = (t - tb)*16;
        const float* fb = ((lev==0)? f0 : (lev==1)? f1 : f2)
                        + (size_t)(b0+by)*96*HW + p0 + l15;

        // gather 3x8 channels, fp32 -> packed bf16 fragments
        bf16x8 Bf[3];
        #pragma unroll
        for (int kt=0;kt<3;kt++){
            const float* fc = fb + (size_t)(kt*32 + rg*8)*HW;
            float x[8];
            #pragma unroll
            for (int j=0;j<8;j++) x[j] = fc[(size_t)j*HW];
            union { unsigned u[4]; bf16x8 v; } cv;
            #pragma unroll
            for (int j=0;j<4;j++) cv.u[j] = f2bf(x[2*j]) | (f2bf(x[2*j+1])<<16);
            Bf[kt] = cv.v;
        }

        size_t A_g = (size_t)(aoff + p0 + l15);
        #pragma unroll
        for (int br=0;br<2;br++){
            int pl = br*2;
            f32x4 acc[3];
            #pragma unroll
            for (int ot=0;ot<3;ot++){ acc[ot][0]=0.f; acc[ot][1]=0.f; acc[ot][2]=0.f; acc[ot][3]=0.f; }
            #pragma unroll
            for (int kt=0;kt<3;kt++)
                #pragma unroll
                for (int ot=0;ot<3;ot++)
                    acc[ot] = MFMA(A[br][ot][kt], Bf[kt], acc[ot]);
            ushort_t* obase = (br ? Or : Oc) + (size_t)by*IMG;
            #pragma unroll
            for (int ot=0;ot<3;ot++){
                f32x4 sv4 = *reinterpret_cast<const f32x4*>(bn1_s + pl*48 + ot*16 + rg*4);
                f32x4 bv4 = *reinterpret_cast<const f32x4*>(bn1_b + pl*48 + ot*16 + rg*4);
                uint2 u;
                u.x = f2bf(relu6f(fmaf(acc[ot][0], sv4[0], bv4[0])))
                   | (f2bf(relu6f(fmaf(acc[ot][1], sv4[1], bv4[1]))) << 16);
                u.y = f2bf(relu6f(fmaf(acc[ot][2], sv4[2], bv4[2])))
                   | (f2bf(relu6f(fmaf(acc[ot][3], sv4[3], bv4[3]))) << 16);
                int chunk = 2*ot + (rg>>1);
                *reinterpret_cast<uint2*>(obase + (size_t)chunk*CHK + A_g*8 + (rg&1)*4) = u;
            }
        }
    }
}

// ---------------------------------------------------------------------------
// Layer-1 pointwise 96->48 + BN + ReLU6 via MFMA, both branches.
// Chunk-major in/out. grid (66, bc, 2), block 256 (4 waves).
// ---------------------------------------------------------------------------
__global__ __launch_bounds__(256) void pw1_kernel(
    const ushort_t* __restrict__ Xc, const ushort_t* __restrict__ Xr,
    ushort_t* __restrict__ Oc, ushort_t* __restrict__ Or,
    const ushort_t* __restrict__ pwW,
    const float* __restrict__ bn1_s, const float* __restrict__ bn1_b)
{
    int br = blockIdx.z, pl = br*2 + 1;
    const ushort_t* W = pwW + (size_t)pl*48*96;
    int lane = threadIdx.x & 63, wv = threadIdx.x >> 6;
    int l15 = lane & 15, rg = lane >> 4;

    bf16x8 A[3][3];
    #pragma unroll
    for (int ot=0; ot<3; ot++)
        #pragma unroll
        for (int kt=0; kt<3; kt++)
            A[ot][kt] = ldb8(W + (size_t)(ot*16 + l15)*96 + kt*32 + rg*8);

    float sv[3][4], bv[3][4];
    #pragma unroll
    for (int ot=0; ot<3; ot++)
        #pragma unroll
        for (int j=0;j<4;j++){
            int ch = ot*16 + rg*4 + j;
            sv[ot][j] = bn1_s[pl*48 + ch];
            bv[ot][j] = bn1_b[pl*48 + ch];
        }

    const ushort_t* X = (br ? Xr : Xc) + (size_t)blockIdx.y*IMG;
    ushort_t* O = (br ? Or : Oc) + (size_t)blockIdx.y*IMG;
    int wg = blockIdx.x*4 + wv;

    #pragma unroll
    for (int i=0;i<2;i++){
        int t = wg*2 + i;
        if (t >= 525) break;
        size_t a = (size_t)(t*16 + l15);
        bf16x8 Bf[3];
        #pragma unroll
        for (int kt=0;kt<3;kt++)
            Bf[kt] = ldb8(X + (size_t)(kt*4 + rg)*CHK + a*8);
        f32x4 acc[3];
        #pragma unroll
        for (int ot=0;ot<3;ot++){ acc[ot][0]=0.f; acc[ot][1]=0.f; acc[ot][2]=0.f; acc[ot][3]=0.f; }
        #pragma unroll
        for (int kt=0;kt<3;kt++)
            #pragma unroll
            for (int ot=0;ot<3;ot++)
                acc[ot] = MFMA(A[ot][kt], Bf[kt], acc[ot]);
        #pragma unroll
        for (int ot=0;ot<3;ot++){
            uint2 u;
            u.x = f2bf(relu6f(fmaf(acc[ot][0], sv[ot][0], bv[ot][0])))
               | (f2bf(relu6f(fmaf(acc[ot][1], sv[ot][1], bv[ot][1]))) << 16);
            u.y = f2bf(relu6f(fmaf(acc[ot][2], sv[ot][2], bv[ot][2])))
               | (f2bf(relu6f(fmaf(acc[ot][3], sv[ot][3], bv[ot][3]))) << 16);
            int chunk = 2*ot + (rg>>1);
            *reinterpret_cast<uint2*>(O + (size_t)chunk*CHK + a*8 + (rg&1)*4) = u;
        }
    }
}

// ---------------------------------------------------------------------------
// Depthwise 3x3 + BN + ReLU6, chunk-major. Reads chunks [0,6) (primary 48ch),
// writes chunks [6,12) (cheap 48ch). grid (33, bc, 2), block 384 = 6 waves;
// wave = chunk (uniform), thread = 4 consecutive anchors. All loads/stores
// are dense consecutive 16B (full line utilization). Branch-free predication.
// ---------------------------------------------------------------------------
__global__ __launch_bounds__(384) void dw_kernel(
    ushort_t* __restrict__ Bc, ushort_t* __restrict__ Br,
    const float* __restrict__ cheap_w,
    const float* __restrict__ bn2_s, const float* __restrict__ bn2_b, int li)
{
    int br = blockIdx.z, pl = br*2 + li;
    int ck = __builtin_amdgcn_readfirstlane((int)threadIdx.x >> 6);   // chunk 0..5
    int s8 = ck*8;

    int qa = blockIdx.x*64 + ((int)threadIdx.x & 63);
    int a0 = qa*4;
    if (a0 >= 8400) return;
    int lev, W, aoff;
    if (a0 < 6400){ lev=0; W=80; aoff=0; }
    else if (a0 < 8000){ lev=1; W=40; aoff=6400; }
    else { lev=2; W=20; aoff=8000; }
    int p = a0 - aoff;
    int h = (lev==0) ? p/80 : (lev==1) ? p/40 : p/20;
    int x0 = p - h*W;                 // multiple of 4; anchors a0..a0+3 same row

    ushort_t* bufbase = (br ? Br : Bc) + (size_t)blockIdx.y*IMG;
    const ushort_t* src = bufbase + (size_t)ck*CHK + (size_t)a0*8;
    ushort_t*       dst = bufbase + (size_t)(6+ck)*CHK + (size_t)a0*8;

    float acc[4][8];
    #pragma unroll
    for (int j=0;j<4;j++)
        #pragma unroll
        for (int c=0;c<8;c++) acc[j][c] = 0.f;

    #pragma unroll
    for (int dy=-1; dy<=1; dy++){
        int hh = h + dy;
        bool rv = (unsigned)hh < (unsigned)W;    // H == W (square levels)
        float xv[6][8];
        #pragma unroll
        for (int i=0;i<6;i++){
            int px = x0 + i - 1;
            bool v = rv && ((unsigned)px < (unsigned)W);
            ptrdiff_t off = v ? (ptrdiff_t)(dy*W + i - 1)*8 : 0;    // address select
            uint4 u = *reinterpret_cast<const uint4*>(src + off);   // unconditional
            u.x = v ? u.x : 0u; u.y = v ? u.y : 0u;
            u.z = v ? u.z : 0u; u.w = v ? u.w : 0u;
            xv[i][0]=bf2f(u.x&0xffffu); xv[i][1]=bf2f(u.x>>16);
            xv[i][2]=bf2f(u.y&0xffffu); xv[i][3]=bf2f(u.y>>16);
            xv[i][4]=bf2f(u.z&0xffffu); xv[i][5]=bf2f(u.z>>16);
            xv[i][6]=bf2f(u.w&0xffffu); xv[i][7]=bf2f(u.w>>16);
        }
        #pragma unroll
        for (int c=0;c<8;c++){
            // wave-uniform indices -> scalar loads (SGPR operands in the FMAs)
            float w0 = cheap_w[(pl*48 + s8 + c)*9 + (dy+1)*3 + 0];
            float w1 = cheap_w[(pl*48 + s8 + c)*9 + (dy+1)*3 + 1];
            float w2 = cheap_w[(pl*48 + s8 + c)*9 + (dy+1)*3 + 2];
            #pragma unroll
            for (int j=0;j<4;j++)
                acc[j][c] = fmaf(xv[j][c], w0,
                            fmaf(xv[j+1][c], w1,
                            fmaf(xv[j+2][c], w2, acc[j][c])));
        }
    }

    float s2v[8], b2v[8];
    #pragma unroll
    for (int c=0;c<8;c++){
        s2v[c] = bn2_s[pl*48 + s8 + c];
        b2v[c] = bn2_b[pl*48 + s8 + c];
    }
    #pragma unroll
    for (int j=0;j<4;j++){
        uint4 o;
        o.x = f2bf(relu6f(fmaf(acc[j][0], s2v[0], b2v[0])))
           | (f2bf(relu6f(fmaf(acc[j][1], s2v[1], b2v[1]))) << 16);
        o.y = f2bf(relu6f(fmaf(acc[j][2], s2v[2], b2v[2])))
           | (f2bf(relu6f(fmaf(acc[j][3], s2v[3], b2v[3]))) << 16);
        o.z = f2bf(relu6f(fmaf(acc[j][4], s2v[4], b2v[4])))
           | (f2bf(relu6f(fmaf(acc[j][5], s2v[5], b2v[5]))) << 16);
        o.w = f2bf(relu6f(fmaf(acc[j][6], s2v[6], b2v[6])))
           | (f2bf(relu6f(fmaf(acc[j][7], s2v[7], b2v[7]))) << 16);
        *reinterpret_cast<uint4*>(dst + j*8) = o;
    }
}

// ---------------------------------------------------------------------------
// Head cls+obj via MFMA. Chunk-major input. grid (66, bc).
// ---------------------------------------------------------------------------
__global__ __launch_bounds__(256) void head_cls_mfma(
    const ushort_t* __restrict__ Xc, const ushort_t* __restrict__ clsW,
    const float* __restrict__ cls_b_all, const float* __restrict__ obj_b_all,
    float* __restrict__ scores, int b0)
{
    int lane = threadIdx.x & 63, wv = threadIdx.x >> 6;
    int l15 = lane & 15, rg = lane >> 4;
    const ushort_t* X = Xc + (size_t)blockIdx.y*IMG;
    float* sbase = scores + (size_t)(b0 + blockIdx.y)*8400*80;
    int wg = blockIdx.x*4 + wv;

    bf16x8 A[6][3];
    float cb[5][4];
    float obv = 0.f;
    int curlev = -1;

    for (int i=0;i<2;i++){
        int t = wg*2 + i;
        if (t >= 525) break;
        int lev = (t < 400) ? 0 : (t < 500) ? 1 : 2;
        if (lev != curlev){
            curlev = lev;
            const ushort_t* Wl = clsW + (size_t)lev*96*96;
            #pragma unroll
            for (int ot=0; ot<6; ot++)
                #pragma unroll
                for (int kt=0; kt<3; kt++)
                    A[ot][kt] = ldb8(Wl + (size_t)(ot*16 + l15)*96 + kt*32 + rg*8);
            #pragma unroll
            for (int ot=0; ot<5; ot++)
                #pragma unroll
                for (int j=0;j<4;j++)
                    cb[ot][j] = cls_b_all[lev*80 + ot*16 + rg*4 + j];
            obv = obj_b_all[lev];
        }
        size_t a = (size_t)(t*16 + l15);
        bf16x8 Bf[3];
        #pragma unroll
        for (int kt=0;kt<3;kt++)
            Bf[kt] = ldb8(X + (size_t)(kt*4 + rg)*CHK + a*8);
        f32x4 acc[6];
        #pragma unroll
        for (int ot=0;ot<6;ot++){ acc[ot][0]=0.f; acc[ot][1]=0.f; acc[ot][2]=0.f; acc[ot][3]=0.f; }
        #pragma unroll
        for (int kt=0;kt<3;kt++)
            #pragma unroll
            for (int ot=0;ot<6;ot++)
                acc[ot] = MFMA(A[ot][kt], Bf[kt], acc[ot]);

        float objp = acc[5][0];                  // row 80 lives in rg==0 lanes
        float objv = __shfl(objp, l15) + obv;    // broadcast to all rgs of this anchor
        float* srow = sbase + a*80;
        #pragma unroll
        for (int ot=0;ot<5;ot++){
            f32x4 o;
            #pragma unroll
            for (int j=0;j<4;j++)
                o[j] = sigmoidf(acc[ot][j] + cb[ot][j] + objv);
            *reinterpret_cast<f32x4*>(srow + ot*16 + rg*4) = o;
        }
    }
}

// ---------------------------------------------------------------------------
// Head reg via MFMA + in-register DFL + boxes. Chunk-major input. grid (66, bc).
// ---------------------------------------------------------------------------
__global__ __launch_bounds__(256) void head_reg_mfma(
    const ushort_t* __restrict__ Xr, const ushort_t* __restrict__ regW,
    const float* __restrict__ reg_b_all, float* __restrict__ boxes, int b0)
{
    int lane = threadIdx.x & 63, wv = threadIdx.x >> 6;
    int l15 = lane & 15, rg = lane >> 4;
    const ushort_t* X = Xr + (size_t)blockIdx.y*IMG;
    float* bbase = boxes + (size_t)(b0 + blockIdx.y)*8400*4;
    int wg = blockIdx.x*4 + wv;

    bf16x8 A[2][3];
    float rb[2][4];
    float sc = 8.f; int aoff = 0, Wd = 80, curlev = -1;

    for (int i=0;i<2;i++){
        int t = wg*2 + i;
        if (t >= 525) break;
        int lev = (t < 400) ? 0 : (t < 500) ? 1 : 2;
        if (lev != curlev){
            curlev = lev;
            const ushort_t* Wl = regW + (size_t)lev*32*96;
            #pragma unroll
            for (int ot=0; ot<2; ot++)
                #pragma unroll
                for (int kt=0; kt<3; kt++)
                    A[ot][kt] = ldb8(Wl + (size_t)(ot*16 + l15)*96 + kt*32 + rg*8);
            #pragma unroll
            for (int ot=0; ot<2; ot++)
                #pragma unroll
                for (int j=0;j<4;j++)
                    rb[ot][j] = reg_b_all[lev*32 + ot*16 + rg*4 + j];
            sc   = (lev==0) ? 8.f : (lev==1) ? 16.f : 32.f;
            aoff = (lev==0) ? 0   : (lev==1) ? 6400 : 8000;
            Wd   = (lev==0) ? 80  : (lev==1) ? 40   : 20;
        }
        int a0 = t*16;
        bf16x8 Bf[3];
        #pragma unroll
        for (int kt=0;kt<3;kt++)
            Bf[kt] = ldb8(X + (size_t)(kt*4 + rg)*CHK + (size_t)(a0 + l15)*8);
        f32x4 acc[2];
        #pragma unroll
        for (int ot=0;ot<2;ot++){ acc[ot][0]=0.f; acc[ot][1]=0.f; acc[ot][2]=0.f; acc[ot][3]=0.f; }
        #pragma unroll
        for (int kt=0;kt<3;kt++)
            #pragma unroll
            for (int ot=0;ot<2;ot++)
                acc[ot] = MFMA(A[ot][kt], Bf[kt], acc[ot]);

        // DFL softmax-expectation, 8-bin groups split across rg-pairs
        float rbase = (float)((rg & 1) * 4);
        float lv[2];
        #pragma unroll
        for (int ot=0;ot<2;ot++){
            float tv[4];
            #pragma unroll
            for (int j=0;j<4;j++) tv[j] = acc[ot][j] + rb[ot][j];
            float m = fmaxf(fmaxf(tv[0],tv[1]), fmaxf(tv[2],tv[3]));
            m = fmaxf(m, __shfl_xor(m, 16));
            float se = 0.f, ne = 0.f;
            #pragma unroll
            for (int j=0;j<4;j++){
                float e = __expf(tv[j] - m);
                se += e; ne = fmaf(e, rbase + (float)j, ne);
            }
            float den = se + __shfl_xor(se, 16);
            float num = ne + __shfl_xor(ne, 16);
            lv[ot] = num / den * sc;
        }
        int a_img = a0 + l15;
        int p = a_img - aoff;
        int hh = (curlev==0) ? p/80 : (curlev==1) ? p/40 : p/20;
        int xx = p - hh*Wd;
        float ax = (xx + 0.5f)*sc, ay = (hh + 0.5f)*sc;
        float v0 = ax - lv[0];
        float v1 = ax + lv[1];
        float w0 = ay - lv[0];
        float w1 = ay + lv[1];
        float y1g = __shfl_xor(w0, 32);
        float y2g = __shfl_xor(w1, 32);
        if (lane < 16){
            f32x4 o; o[0] = v0; o[1] = y1g; o[2] = v1; o[3] = y2g;
            *reinterpret_cast<f32x4*>(bbase + (size_t)a_img*4) = o;
        }
    }
}

// ---------------------------------------------------------------------------
extern "C" void kernel_launch(void* const* d_in, const int* in_sizes, int n_in,
                              void* d_out, int out_size, void* d_ws, size_t ws_size,
                              hipStream_t stream)
{
    const float* f0        = (const float*)d_in[0];
    const float* f1        = (const float*)d_in[1];
    const float* f2        = (const float*)d_in[2];
    const float* primary_w = (const float*)d_in[3];
    const float* bn1_s     = (const float*)d_in[4];
    const float* bn1_b     = (const float*)d_in[5];
    const float* cheap_w   = (const float*)d_in[6];
    const float* bn2_s     = (const float*)d_in[7];
    const float* bn2_b     = (const float*)d_in[8];
    const float* cls_w     = (const float*)d_in[9];
    const float* cls_b     = (const float*)d_in[10];
    const float* obj_w     = (const float*)d_in[11];
    const float* obj_b     = (const float*)d_in[12];
    const float* reg_w     = (const float*)d_in[13];
    const float* reg_b     = (const float*)d_in[14];

    const int B = 16;
    float* boxes  = (float*)d_out;
    float* scores = boxes + (size_t)16*8400*4;

    ushort_t* pwW  = (ushort_t*)d_ws;
    ushort_t* clsW = pwW + 18432;
    ushort_t* regW = clsW + 27648;
    ushort_t* bufs = regW + 9216;
    size_t used0 = (size_t)55296*2;

    int bc = 16;
    while (bc > 1 && used0 + 4*(size_t)bc*IMG*2 > ws_size) bc >>= 1;
    size_t perBuf = (size_t)bc*IMG;
    ushort_t* C0 = bufs;
    ushort_t* R0 = C0 + perBuf;
    ushort_t* C1 = R0 + perBuf;
    ushort_t* R1 = C1 + perBuf;

    prep_kernel<<<108, 256, 0, stream>>>(primary_w, cls_w, obj_w, reg_w, pwW, clsW, regW);

    for (int b0 = 0; b0 < B; b0 += bc){
        pw0_kernel<<<dim3(66, bc), 256, 0, stream>>>(
            f0, f1, f2, C0, R0, pwW, bn1_s, bn1_b, b0);
        dw_kernel<<<dim3(33, bc, 2), 384, 0, stream>>>(C0, R0, cheap_w, bn2_s, bn2_b, 0);
        pw1_kernel<<<dim3(66, bc, 2), 256, 0, stream>>>(
            C0, R0, C1, R1, pwW, bn1_s, bn1_b);
        dw_kernel<<<dim3(33, bc, 2), 384, 0, stream>>>(C1, R1, cheap_w, bn2_s, bn2_b, 1);
        head_cls_mfma<<<dim3(66, bc), 256, 0, stream>>>(
            C1, clsW, cls_b, obj_b, scores, b0);
        head_reg_mfma<<<dim3(66, bc), 256, 0, stream>>>(
            R1, regW, reg_b, boxes, b0);
    }
}

// Round 9
// 94.398 us; speedup vs baseline: 9.6332x; 1.1796x over previous
//
#include <hip/hip_runtime.h>
#include <math.h>

typedef unsigned short ushort_t;
typedef __attribute__((ext_vector_type(8))) short bf16x8;
typedef __attribute__((ext_vector_type(4))) float f32x4;

#define CHK 67200            // chunk plane stride in ushorts (8400 anchors * 8 ch)
#define IMG6 403200          // per-image buffer: 6 primary chunks only

__device__ __forceinline__ float relu6f(float x){ return fminf(fmaxf(x,0.f),6.f); }
__device__ __forceinline__ float sigmoidf(float x){ return 1.f/(1.f+__expf(-x)); }
__device__ __forceinline__ float bf2f(unsigned u){ union{unsigned i; float f;}v; v.i=u<<16; return v.f; }
__device__ __forceinline__ unsigned f2bf(float f){ union{float f; unsigned i;}v; v.f=f;
    unsigned r = v.i + 0x7fff + ((v.i>>16)&1); return r>>16; }
__device__ __forceinline__ bf16x8 ldb8(const ushort_t* p){ return *reinterpret_cast<const bf16x8*>(p); }
#define MFMA(a,b,c) __builtin_amdgcn_mfma_f32_16x16x32_bf16((a),(b),(c),0,0,0)

// ---------------------------------------------------------------------------
// Weight prep (runs once): fp32 -> bf16.
// ---------------------------------------------------------------------------
__global__ __launch_bounds__(256) void prep_kernel(
    const float* __restrict__ primary_w, const float* __restrict__ cls_w,
    const float* __restrict__ obj_w, const float* __restrict__ reg_w,
    ushort_t* __restrict__ pwW, ushort_t* __restrict__ clsW, ushort_t* __restrict__ regW)
{
    int i = blockIdx.x*256 + threadIdx.x;
    if (i < 18432) pwW[i] = (ushort_t)f2bf(primary_w[i]);
    if (i < 27648){
        int lev = i/9216, rem = i - lev*9216, row = rem/96, c = rem - row*96;
        float v = (row < 80) ? cls_w[(lev*80 + row)*96 + c]
                : (row == 80) ? obj_w[lev*96 + c] : 0.f;
        clsW[i] = (ushort_t)f2bf(v);
    }
    if (i < 9216) regW[i] = (ushort_t)f2bf(reg_w[i]);
}

// ---------------------------------------------------------------------------
// Tile decode: 67 blocks of 128 anchors (50 lev0 / 13 lev1 / 4 lev2).
// ---------------------------------------------------------------------------
__device__ __forceinline__ void tile_decode(int bx, int& lev, int& pb, int& HW,
                                            int& W, int& aoff, int& nt)
{
    if (bx < 50){ lev=0; pb = bx*128;      HW=6400; W=80; aoff=0;    }
    else if (bx < 63){ lev=1; pb = (bx-50)*128; HW=1600; W=40; aoff=6400; }
    else { lev=2; pb = (bx-63)*128; HW=400; W=20; aoff=8000; }
    nt = HW - pb; if (nt > 128) nt = 128;
}

// ---------------------------------------------------------------------------
// dw stage: 3x3 depthwise on 6 primary chunks of X (global, halo ok) for a
// 128-anchor tile -> cheap 48ch into LDS xs[a][56] (slots 0..5 of 8ch).
// 192 threads active: ck = tid>>5 (chunk), q = tid&31 (anchor quad).
// ---------------------------------------------------------------------------
__device__ __forceinline__ void dw_stage(
    const ushort_t* __restrict__ X, ushort_t* __restrict__ xs,
    const float* __restrict__ cheap_w,
    const float* __restrict__ bn2_s, const float* __restrict__ bn2_b,
    int pl, int lev, int pb, int W, int aoff, int nt, int tid)
{
    int ck = tid >> 5;          // 0..7 (6 used)
    int q  = tid & 31;
    if (ck >= 6 || q*4 >= nt) return;
    int p = pb + q*4;
    int h = (lev==0) ? p/80 : (lev==1) ? p/40 : p/20;
    int x0 = p - h*W;           // multiple of 4; 4 anchors same row
    int s8 = ck*8;
    const ushort_t* src = X + (size_t)ck*CHK + (size_t)(aoff+p)*8;

    float acc[4][8];
    #pragma unroll
    for (int j=0;j<4;j++)
        #pragma unroll
        for (int c=0;c<8;c++) acc[j][c] = 0.f;

    #pragma unroll
    for (int dy=-1; dy<=1; dy++){
        int hh = h + dy;
        bool rv = (unsigned)hh < (unsigned)W;    // H == W (square levels)
        float xv[6][8];
        #pragma unroll
        for (int i=0;i<6;i++){
            int px = x0 + i - 1;
            bool v = rv && ((unsigned)px < (unsigned)W);
            ptrdiff_t off = v ? (ptrdiff_t)(dy*W + i - 1)*8 : 0;    // address select
            uint4 u = *reinterpret_cast<const uint4*>(src + off);   // unconditional
            u.x = v ? u.x : 0u; u.y = v ? u.y : 0u;
            u.z = v ? u.z : 0u; u.w = v ? u.w : 0u;
            xv[i][0]=bf2f(u.x&0xffffu); xv[i][1]=bf2f(u.x>>16);
            xv[i][2]=bf2f(u.y&0xffffu); xv[i][3]=bf2f(u.y>>16);
            xv[i][4]=bf2f(u.z&0xffffu); xv[i][5]=bf2f(u.z>>16);
            xv[i][6]=bf2f(u.w&0xffffu); xv[i][7]=bf2f(u.w>>16);
        }
        #pragma unroll
        for (int c=0;c<8;c++){
            float w0 = cheap_w[(pl*48 + s8 + c)*9 + (dy+1)*3 + 0];
            float w1 = cheap_w[(pl*48 + s8 + c)*9 + (dy+1)*3 + 1];
            float w2 = cheap_w[(pl*48 + s8 + c)*9 + (dy+1)*3 + 2];
            #pragma unroll
            for (int j=0;j<4;j++)
                acc[j][c] = fmaf(xv[j][c], w0,
                            fmaf(xv[j+1][c], w1,
                            fmaf(xv[j+2][c], w2, acc[j][c])));
        }
    }

    float s2v[8], b2v[8];
    #pragma unroll
    for (int c=0;c<8;c++){
        s2v[c] = bn2_s[pl*48 + s8 + c];
        b2v[c] = bn2_b[pl*48 + s8 + c];
    }
    #pragma unroll
    for (int j=0;j<4;j++){
        uint4 o;
        o.x = f2bf(relu6f(fmaf(acc[j][0], s2v[0], b2v[0])))
           | (f2bf(relu6f(fmaf(acc[j][1], s2v[1], b2v[1]))) << 16);
        o.y = f2bf(relu6f(fmaf(acc[j][2], s2v[2], b2v[2])))
           | (f2bf(relu6f(fmaf(acc[j][3], s2v[3], b2v[3]))) << 16);
        o.z = f2bf(relu6f(fmaf(acc[j][4], s2v[4], b2v[4])))
           | (f2bf(relu6f(fmaf(acc[j][5], s2v[5], b2v[5]))) << 16);
        o.w = f2bf(relu6f(fmaf(acc[j][6], s2v[6], b2v[6])))
           | (f2bf(relu6f(fmaf(acc[j][7], s2v[7], b2v[7]))) << 16);
        *reinterpret_cast<uint4*>(xs + (size_t)(q*4+j)*56 + s8) = o;
    }
}

// B-fragment gather: primary from global chunks, cheap from LDS.
__device__ __forceinline__ void gather_B(
    const ushort_t* __restrict__ X, const ushort_t* __restrict__ xs,
    int a_l, size_t A_g, int rg, bf16x8* Bf)
{
    Bf[0] = ldb8(X + (size_t)rg*CHK + A_g*8);
    Bf[1] = (rg < 2) ? ldb8(X + (size_t)(4+rg)*CHK + A_g*8)
                     : ldb8(xs + (size_t)a_l*56 + (rg-2)*8);
    Bf[2] = ldb8(xs + (size_t)a_l*56 + 16 + rg*8);
}

// ---------------------------------------------------------------------------
// Layer-0 pointwise via MFMA, LDS-free gather from CHW fp32.
// grid (66, bc), block 256. Output: 6 primary chunks of C0/R0.
// ---------------------------------------------------------------------------
__global__ __launch_bounds__(256) void pw0_kernel(
    const float* __restrict__ f0, const float* __restrict__ f1, const float* __restrict__ f2,
    ushort_t* __restrict__ Oc, ushort_t* __restrict__ Or,
    const ushort_t* __restrict__ pwW,
    const float* __restrict__ bn1_s, const float* __restrict__ bn1_b, int b0)
{
    int lane = threadIdx.x & 63, wv = threadIdx.x >> 6;
    int l15 = lane & 15, rg = lane >> 4;
    int wg = blockIdx.x*4 + wv;
    int by = blockIdx.y;

    bf16x8 A[2][3][3];
    #pragma unroll
    for (int br=0;br<2;br++)
        #pragma unroll
        for (int ot=0; ot<3; ot++)
            #pragma unroll
            for (int kt=0; kt<3; kt++)
                A[br][ot][kt] = ldb8(pwW + (size_t)(br*96 + ot*16 + l15)*96 + kt*32 + rg*8);

    #pragma unroll
    for (int i=0;i<2;i++){
        int t = wg*2 + i;
        if (t >= 525) break;
        int lev  = (t < 400) ? 0 : (t < 500) ? 1 : 2;
        int HW   = (lev==0) ? 6400 : (lev==1) ? 1600 : 400;
        int tb   = (lev==0) ? 0    : (lev==1) ? 400  : 500;
        int aoff = (lev==0) ? 0    : (lev==1) ? 6400 : 8000;
        int p0   = (t - tb)*16;
        const float* fb = ((lev==0)? f0 : (lev==1)? f1 : f2)
                        + (size_t)(b0+by)*96*HW + p0 + l15;

        bf16x8 Bf[3];
        #pragma unroll
        for (int kt=0;kt<3;kt++){
            const float* fc = fb + (size_t)(kt*32 + rg*8)*HW;
            float x[8];
            #pragma unroll
            for (int j=0;j<8;j++) x[j] = fc[(size_t)j*HW];
            union { unsigned u[4]; bf16x8 v; } cv;
            #pragma unroll
            for (int j=0;j<4;j++) cv.u[j] = f2bf(x[2*j]) | (f2bf(x[2*j+1])<<16);
            Bf[kt] = cv.v;
        }

        size_t A_g = (size_t)(aoff + p0 + l15);
        #pragma unroll
        for (int br=0;br<2;br++){
            int pl = br*2;
            f32x4 acc[3];
            #pragma unroll
            for (int ot=0;ot<3;ot++){ acc[ot][0]=0.f; acc[ot][1]=0.f; acc[ot][2]=0.f; acc[ot][3]=0.f; }
            #pragma unroll
            for (int kt=0;kt<3;kt++)
                #pragma unroll
                for (int ot=0;ot<3;ot++)
                    acc[ot] = MFMA(A[br][ot][kt], Bf[kt], acc[ot]);
            ushort_t* obase = (br ? Or : Oc) + (size_t)by*IMG6;
            #pragma unroll
            for (int ot=0;ot<3;ot++){
                f32x4 sv4 = *reinterpret_cast<const f32x4*>(bn1_s + pl*48 + ot*16 + rg*4);
                f32x4 bv4 = *reinterpret_cast<const f32x4*>(bn1_b + pl*48 + ot*16 + rg*4);
                uint2 u;
                u.x = f2bf(relu6f(fmaf(acc[ot][0], sv4[0], bv4[0])))
                   | (f2bf(relu6f(fmaf(acc[ot][1], sv4[1], bv4[1]))) << 16);
                u.y = f2bf(relu6f(fmaf(acc[ot][2], sv4[2], bv4[2])))
                   | (f2bf(relu6f(fmaf(acc[ot][3], sv4[3], bv4[3]))) << 16);
                int chunk = 2*ot + (rg>>1);
                *reinterpret_cast<uint2*>(obase + (size_t)chunk*CHK + A_g*8 + (rg&1)*4) = u;
            }
        }
    }
}

// ---------------------------------------------------------------------------
// Fused dw(layer0) + pw(layer1). grid (67, bc, 2), block 256.
// Phase 1: dw -> LDS. Phase 2: pw1 MFMA, output 6 primary chunks of C1/R1.
// ---------------------------------------------------------------------------
__global__ __launch_bounds__(256) void dwpw1_kernel(
    const ushort_t* __restrict__ Xc, const ushort_t* __restrict__ Xr,
    ushort_t* __restrict__ Oc, ushort_t* __restrict__ Or,
    const ushort_t* __restrict__ pwW,
    const float* __restrict__ cheap_w,
    const float* __restrict__ bn2_s, const float* __restrict__ bn2_b,
    const float* __restrict__ bn1_s, const float* __restrict__ bn1_b)
{
    __shared__ __align__(16) ushort_t xs[128*56];
    int br = blockIdx.z, by = blockIdx.y;
    int lev, pb, HW, W, aoff, nt;
    tile_decode(blockIdx.x, lev, pb, HW, W, aoff, nt);

    const ushort_t* X = (br ? Xr : Xc) + (size_t)by*IMG6;
    ushort_t* O = (br ? Or : Oc) + (size_t)by*IMG6;
    int tid = threadIdx.x;

    dw_stage(X, xs, cheap_w, bn2_s, bn2_b, br*2, lev, pb, W, aoff, nt, tid);
    __syncthreads();

    int lane = tid & 63, wv = tid >> 6;
    int l15 = lane & 15, rg = lane >> 4;
    int pl = br*2 + 1;
    const ushort_t* Wp = pwW + (size_t)pl*48*96;

    bf16x8 A[3][3];
    #pragma unroll
    for (int ot=0; ot<3; ot++)
        #pragma unroll
        for (int kt=0; kt<3; kt++)
            A[ot][kt] = ldb8(Wp + (size_t)(ot*16 + l15)*96 + kt*32 + rg*8);

    #pragma unroll
    for (int i=0;i<2;i++){
        int tl = wv + i*4;
        if (tl*16 >= nt) continue;
        int a_l = tl*16 + l15;
        size_t A_g = (size_t)(aoff + pb + a_l);
        bf16x8 Bf[3];
        gather_B(X, xs, a_l, A_g, rg, Bf);
        f32x4 acc[3];
        #pragma unroll
        for (int ot=0;ot<3;ot++){ acc[ot][0]=0.f; acc[ot][1]=0.f; acc[ot][2]=0.f; acc[ot][3]=0.f; }
        #pragma unroll
        for (int kt=0;kt<3;kt++)
            #pragma unroll
            for (int ot=0;ot<3;ot++)
                acc[ot] = MFMA(A[ot][kt], Bf[kt], acc[ot]);
        #pragma unroll
        for (int ot=0;ot<3;ot++){
            f32x4 sv4 = *reinterpret_cast<const f32x4*>(bn1_s + pl*48 + ot*16 + rg*4);
            f32x4 bv4 = *reinterpret_cast<const f32x4*>(bn1_b + pl*48 + ot*16 + rg*4);
            uint2 u;
            u.x = f2bf(relu6f(fmaf(acc[ot][0], sv4[0], bv4[0])))
               | (f2bf(relu6f(fmaf(acc[ot][1], sv4[1], bv4[1]))) << 16);
            u.y = f2bf(relu6f(fmaf(acc[ot][2], sv4[2], bv4[2])))
               | (f2bf(relu6f(fmaf(acc[ot][3], sv4[3], bv4[3]))) << 16);
            int chunk = 2*ot + (rg>>1);
            *reinterpret_cast<uint2*>(O + (size_t)chunk*CHK + A_g*8 + (rg&1)*4) = u;
        }
    }
}

// ---------------------------------------------------------------------------
// Fused dw(layer1) + heads. grid (67, bc, 2): z=0 cls head on C1, z=1 reg
// head on R1. Phase 1: dw -> LDS. Phase 2: head MFMA + epilogue.
// ---------------------------------------------------------------------------
__global__ __launch_bounds__(256) void dwhead_kernel(
    const ushort_t* __restrict__ Xc, const ushort_t* __restrict__ Xr,
    const ushort_t* __restrict__ clsW, const ushort_t* __restrict__ regW,
    const float* __restrict__ cheap_w,
    const float* __restrict__ bn2_s, const float* __restrict__ bn2_b,
    const float* __restrict__ cls_b_all, const float* __restrict__ obj_b_all,
    const float* __restrict__ reg_b_all,
    float* __restrict__ scores, float* __restrict__ boxes, int b0)
{
    __shared__ __align__(16) ushort_t xs[128*56];
    int br = blockIdx.z, by = blockIdx.y;
    int lev, pb, HW, W, aoff, nt;
    tile_decode(blockIdx.x, lev, pb, HW, W, aoff, nt);

    const ushort_t* X = (br ? Xr : Xc) + (size_t)by*IMG6;
    int tid = threadIdx.x;

    dw_stage(X, xs, cheap_w, bn2_s, bn2_b, br*2 + 1, lev, pb, W, aoff, nt, tid);
    __syncthreads();

    int lane = tid & 63, wv = tid >> 6;
    int l15 = lane & 15, rg = lane >> 4;

    if (br == 0){
        // ----- cls + obj head -----
        const ushort_t* Wl = clsW + (size_t)lev*96*96;
        bf16x8 A[6][3];
        #pragma unroll
        for (int ot=0; ot<6; ot++)
            #pragma unroll
            for (int kt=0; kt<3; kt++)
                A[ot][kt] = ldb8(Wl + (size_t)(ot*16 + l15)*96 + kt*32 + rg*8);
        float cb[5][4];
        #pragma unroll
        for (int ot=0; ot<5; ot++)
            #pragma unroll
            for (int j=0;j<4;j++)
                cb[ot][j] = cls_b_all[lev*80 + ot*16 + rg*4 + j];
        float obv = obj_b_all[lev];
        float* sbase = scores + (size_t)(b0 + by)*8400*80;

        #pragma unroll
        for (int i=0;i<2;i++){
            int tl = wv + i*4;
            if (tl*16 >= nt) continue;
            int a_l = tl*16 + l15;
            size_t A_g = (size_t)(aoff + pb + a_l);
            bf16x8 Bf[3];
            gather_B(X, xs, a_l, A_g, rg, Bf);
            f32x4 acc[6];
            #pragma unroll
            for (int ot=0;ot<6;ot++){ acc[ot][0]=0.f; acc[ot][1]=0.f; acc[ot][2]=0.f; acc[ot][3]=0.f; }
            #pragma unroll
            for (int kt=0;kt<3;kt++)
                #pragma unroll
                for (int ot=0;ot<6;ot++)
                    acc[ot] = MFMA(A[ot][kt], Bf[kt], acc[ot]);
            float objp = acc[5][0];
            float objv = __shfl(objp, l15) + obv;
            float* srow = sbase + A_g*80;
            #pragma unroll
            for (int ot=0;ot<5;ot++){
                f32x4 o;
                #pragma unroll
                for (int j=0;j<4;j++)
                    o[j] = sigmoidf(acc[ot][j] + cb[ot][j] + objv);
                *reinterpret_cast<f32x4*>(srow + ot*16 + rg*4) = o;
            }
        }
    } else {
        // ----- reg head + DFL + boxes -----
        const ushort_t* Wl = regW + (size_t)lev*32*96;
        bf16x8 A[2][3];
        #pragma unroll
        for (int ot=0; ot<2; ot++)
            #pragma unroll
            for (int kt=0; kt<3; kt++)
                A[ot][kt] = ldb8(Wl + (size_t)(ot*16 + l15)*96 + kt*32 + rg*8);
        float rb[2][4];
        #pragma unroll
        for (int ot=0; ot<2; ot++)
            #pragma unroll
            for (int j=0;j<4;j++)
                rb[ot][j] = reg_b_all[lev*32 + ot*16 + rg*4 + j];
        float sc = (lev==0) ? 8.f : (lev==1) ? 16.f : 32.f;
        float* bbase = boxes + (size_t)(b0 + by)*8400*4;

        #pragma unroll
        for (int i=0;i<2;i++){
            int tl = wv + i*4;
            if (tl*16 >= nt) continue;
            int a_l = tl*16 + l15;
            size_t A_g = (size_t)(aoff + pb + a_l);
            bf16x8 Bf[3];
            gather_B(X, xs, a_l, A_g, rg, Bf);
            f32x4 acc[2];
            #pragma unroll
            for (int ot=0;ot<2;ot++){ acc[ot][0]=0.f; acc[ot][1]=0.f; acc[ot][2]=0.f; acc[ot][3]=0.f; }
            #pragma unroll
            for (int kt=0;kt<3;kt++)
                #pragma unroll
                for (int ot=0;ot<2;ot++)
                    acc[ot] = MFMA(A[ot][kt], Bf[kt], acc[ot]);

            float rbase = (float)((rg & 1) * 4);
            float lv[2];
            #pragma unroll
            for (int ot=0;ot<2;ot++){
                float tv[4];
                #pragma unroll
                for (int j=0;j<4;j++) tv[j] = acc[ot][j] + rb[ot][j];
                float m = fmaxf(fmaxf(tv[0],tv[1]), fmaxf(tv[2],tv[3]));
                m = fmaxf(m, __shfl_xor(m, 16));
                float se = 0.f, ne = 0.f;
                #pragma unroll
                for (int j=0;j<4;j++){
                    float e = __expf(tv[j] - m);
                    se += e; ne = fmaf(e, rbase + (float)j, ne);
                }
                float den = se + __shfl_xor(se, 16);
                float num = ne + __shfl_xor(ne, 16);
                lv[ot] = num / den * sc;
            }
            int p = pb + a_l;
            int hh = (lev==0) ? p/80 : (lev==1) ? p/40 : p/20;
            int xx = p - hh*W;
            float ax = (xx + 0.5f)*sc, ay = (hh + 0.5f)*sc;
            float v0 = ax - lv[0];
            float v1 = ax + lv[1];
            float w0 = ay - lv[0];
            float w1 = ay + lv[1];
            float y1g = __shfl_xor(w0, 32);
            float y2g = __shfl_xor(w1, 32);
            if (lane < 16){
                f32x4 o; o[0] = v0; o[1] = y1g; o[2] = v1; o[3] = y2g;
                *reinterpret_cast<f32x4*>(bbase + A_g*4) = o;
            }
        }
    }
}

// ---------------------------------------------------------------------------
extern "C" void kernel_launch(void* const* d_in, const int* in_sizes, int n_in,
                              void* d_out, int out_size, void* d_ws, size_t ws_size,
                              hipStream_t stream)
{
    const float* f0        = (const float*)d_in[0];
    const float* f1        = (const float*)d_in[1];
    const float* f2        = (const float*)d_in[2];
    const float* primary_w = (const float*)d_in[3];
    const float* bn1_s     = (const float*)d_in[4];
    const float* bn1_b     = (const float*)d_in[5];
    const float* cheap_w   = (const float*)d_in[6];
    const float* bn2_s     = (const float*)d_in[7];
    const float* bn2_b     = (const float*)d_in[8];
    const float* cls_w     = (const float*)d_in[9];
    const float* cls_b     = (const float*)d_in[10];
    const float* obj_w     = (const float*)d_in[11];
    const float* obj_b     = (const float*)d_in[12];
    const float* reg_w     = (const float*)d_in[13];
    const float* reg_b     = (const float*)d_in[14];

    const int B = 16;
    float* boxes  = (float*)d_out;
    float* scores = boxes + (size_t)16*8400*4;

    ushort_t* pwW  = (ushort_t*)d_ws;
    ushort_t* clsW = pwW + 18432;
    ushort_t* regW = clsW + 27648;
    ushort_t* bufs = regW + 9216;
    size_t used0 = (size_t)55296*2;

    int bc = 16;
    while (bc > 1 && used0 + 4*(size_t)bc*IMG6*2 > ws_size) bc >>= 1;
    size_t perBuf = (size_t)bc*IMG6;
    ushort_t* C0 = bufs;
    ushort_t* R0 = C0 + perBuf;
    ushort_t* C1 = R0 + perBuf;
    ushort_t* R1 = C1 + perBuf;

    prep_kernel<<<108, 256, 0, stream>>>(primary_w, cls_w, obj_w, reg_w, pwW, clsW, regW);

    for (int b0 = 0; b0 < B; b0 += bc){
        pw0_kernel<<<dim3(66, bc), 256, 0, stream>>>(
            f0, f1, f2, C0, R0, pwW, bn1_s, bn1_b, b0);
        dwpw1_kernel<<<dim3(67, bc, 2), 256, 0, stream>>>(
            C0, R0, C1, R1, pwW, cheap_w, bn2_s, bn2_b, bn1_s, bn1_b);
        dwhead_kernel<<<dim3(67, bc, 2), 256, 0, stream>>>(
            C1, R1, clsW, regW, cheap_w, bn2_s, bn2_b,
            cls_b, obj_b, reg_b, scores, boxes, b0);
    }
}